// Round 2
// baseline (848.800 us; speedup 1.0000x reference)
//
#include <hip/hip_runtime.h>
#include <hip/hip_bf16.h>

#define NNODES 20000
#define NEDGES 160000
#define BQ     64
#define FTEXT  300
#define HIDDIM 1024
#define OUTDIM 1664

// ---------------- degree + count (one pass over edges) ----------------
__global__ void degcnt_kernel(const int* __restrict__ dst, const float* __restrict__ w,
                              float* __restrict__ deg, int* __restrict__ cnt, int E) {
    int e = blockIdx.x * blockDim.x + threadIdx.x;
    if (e < E) {
        int d = dst[e];
        atomicAdd(&deg[d], w[e]);
        atomicAdd(&cnt[d], 1);
    }
}

__global__ void norm_kernel(const int* __restrict__ src, const int* __restrict__ dst,
                            const float* __restrict__ w, const float* __restrict__ deg,
                            float* __restrict__ nrm, int E) {
    int e = blockIdx.x * blockDim.x + threadIdx.x;
    if (e < E) {
        float ds = deg[src[e]], dd = deg[dst[e]];
        float is = ds > 0.f ? rsqrtf(ds) : 0.f;
        float id = dd > 0.f ? rsqrtf(dd) : 0.f;
        nrm[e] = is * w[e] * id;
    }
}

// ---------------- CSR build (group edges by dst) ----------------
__global__ void scan_kernel(const int* __restrict__ cnt, int* __restrict__ row_start, int N) {
    __shared__ int partial[256];
    int t = threadIdx.x;
    int chunk = (N + 255) / 256;
    int begin = t * chunk;
    int end = begin + chunk; if (end > N) end = N;
    int s = 0;
    for (int i = begin; i < end; i++) s += cnt[i];
    partial[t] = s;
    __syncthreads();
    for (int off = 1; off < 256; off <<= 1) {
        int v = (t >= off) ? partial[t - off] : 0;
        __syncthreads();
        partial[t] += v;
        __syncthreads();
    }
    int base = (t == 0) ? 0 : partial[t - 1];
    int run = base;
    for (int i = begin; i < end; i++) { row_start[i] = run; run += cnt[i]; }
    if (t == 255) row_start[N] = partial[255];
}

__global__ void fill_kernel(const int* __restrict__ dst, const int* __restrict__ row_start,
                            int* __restrict__ cursor, int* __restrict__ csr, int E) {
    int e = blockIdx.x * blockDim.x + threadIdx.x;
    if (e < E) {
        int d = dst[e];
        int pos = atomicAdd(&cursor[d], 1);
        csr[row_start[d] + pos] = e;
    }
}

// ---------------- aggregation of node_features: aggNF[d,:] = sum nrm[e]*nf[src[e],:]
// F=300 -> 75 float4 per row (alignment: 300*4 = 1200 bytes, 16B-divisible)
__global__ __launch_bounds__(128) void aggnf_kernel(const float* __restrict__ nf,
        const int* __restrict__ row_start, const int* __restrict__ csr,
        const int* __restrict__ src, const float* __restrict__ nrm,
        float* __restrict__ out, int F4) {
    int d = blockIdx.x;
    int t = threadIdx.x;
    int s0 = row_start[d], s1 = row_start[d + 1];
    for (int f4 = t; f4 < F4; f4 += 128) {
        float4 acc = make_float4(0.f, 0.f, 0.f, 0.f);
        for (int idx = s0; idx < s1; idx++) {
            int e = csr[idx];
            float w = nrm[e];
            float4 hv = ((const float4*)(nf + (long)src[e] * (F4 * 4)))[f4];
            acc.x += hv.x * w; acc.y += hv.y * w; acc.z += hv.z * w; acc.w += hv.w * w;
        }
        ((float4*)(out + (long)d * (F4 * 4)))[f4] = acc;
    }
}

// ---------------- generic fp32 tiled GEMM ----------------
// BT=0: C[MxN] = A[MxK] @ B[KxN].  BT=1: C = A @ B^T, B is [NxK].
// EPI=1: C = leaky_relu(C + bias[n], 0.2)
#define TS 64
#define KS 16
template<int BT, int EPI>
__global__ __launch_bounds__(256) void gemm_tile(const float* __restrict__ A,
        const float* __restrict__ B, const float* __restrict__ bias,
        float* __restrict__ C, int M, int N, int K) {
    __shared__ float As[KS][TS + 4];
    __shared__ float Bs[KS][TS + 4];
    int t = threadIdx.x;
    int m0 = blockIdx.y * TS;
    int n0 = blockIdx.x * TS;
    int tx = t % 16, ty = t / 16;
    float acc[4][4] = {};
    for (int k0 = 0; k0 < K; k0 += KS) {
        #pragma unroll
        for (int i = 0; i < 4; i++) {
            int idx = i * 256 + t;
            int kk = idx % KS;
            int m = idx / KS;
            float v = 0.f;
            int gm = m0 + m, gk = k0 + kk;
            if (gm < M && gk < K) v = A[(long)gm * K + gk];
            As[kk][m] = v;
        }
        #pragma unroll
        for (int i = 0; i < 4; i++) {
            int idx = i * 256 + t;
            float v = 0.f;
            if (BT) {
                int kk = idx % KS;
                int n = idx / KS;
                int gn = n0 + n, gk = k0 + kk;
                if (gn < N && gk < K) v = B[(long)gn * K + gk];
                Bs[kk][n] = v;
            } else {
                int n = idx % TS;
                int kk = idx / TS;
                int gn = n0 + n, gk = k0 + kk;
                if (gn < N && gk < K) v = B[(long)gk * N + gn];
                Bs[kk][n] = v;
            }
        }
        __syncthreads();
        #pragma unroll
        for (int kk = 0; kk < KS; kk++) {
            float a[4], b[4];
            #pragma unroll
            for (int i = 0; i < 4; i++) a[i] = As[kk][ty * 4 + i];
            #pragma unroll
            for (int j = 0; j < 4; j++) b[j] = Bs[kk][tx * 4 + j];
            #pragma unroll
            for (int i = 0; i < 4; i++)
                #pragma unroll
                for (int j = 0; j < 4; j++)
                    acc[i][j] += a[i] * b[j];
        }
        __syncthreads();
    }
    #pragma unroll
    for (int i = 0; i < 4; i++) {
        int gm = m0 + ty * 4 + i;
        if (gm >= M) continue;
        #pragma unroll
        for (int j = 0; j < 4; j++) {
            int gn = n0 + tx * 4 + j;
            if (gn >= N) continue;
            float v = acc[i][j];
            if (EPI) {
                v += bias[gn];
                v = v >= 0.f ? v : 0.2f * v;
            }
            C[(long)gm * N + gn] = v;
        }
    }
}

// ---------------- c[b] = sum_f img[b,f] * b2[f]  (64 blocks x 64 lanes) ------
__global__ __launch_bounds__(64) void cvec_kernel(const float* __restrict__ img,
        const float* __restrict__ b2, float* __restrict__ c, int K) {
    int b = blockIdx.x;
    int l = threadIdx.x;
    float v = 0.f;
    for (int f = l; f < K; f += 64) v += img[(long)b * K + f] * b2[f];
    for (int off = 32; off > 0; off >>= 1) v += __shfl_down(v, off);
    if (l == 0) c[b] = v;
}

// ---------------- out[b,d] = sum_{e:dst=d} nrm[e]*Y[src[e],b] + c[b] --------
// one wave per destination node; lane = b
__global__ __launch_bounds__(64) void outagg_kernel(const float* __restrict__ Y,
        const int* __restrict__ row_start, const int* __restrict__ csr,
        const int* __restrict__ src, const float* __restrict__ nrm,
        const float* __restrict__ c, float* __restrict__ out, int N) {
    int d = blockIdx.x;
    int b = threadIdx.x;
    int s0 = row_start[d], s1 = row_start[d + 1];
    float acc = 0.f;
    for (int idx = s0; idx < s1; idx++) {
        int e = csr[idx];
        acc += nrm[e] * Y[(long)src[e] * 64 + b];
    }
    out[(long)b * N + d] = acc + c[b];
}

extern "C" void kernel_launch(void* const* d_in, const int* in_sizes, int n_in,
                              void* d_out, int out_size, void* d_ws, size_t ws_size,
                              hipStream_t stream) {
    const float* img_feat      = (const float*)d_in[0];
    const float* node_features = (const float*)d_in[1];
    const int*   edge_src      = (const int*)d_in[2];
    const int*   edge_dst      = (const int*)d_in[3];
    const float* edge_weight   = (const float*)d_in[4];
    const float* W1            = (const float*)d_in[5];
    const float* b1            = (const float*)d_in[6];
    const float* W2            = (const float*)d_in[7];
    const float* b2            = (const float*)d_in[8];
    float* out = (float*)d_out;

    const int N = NNODES, E = NEDGES;

    char* ws = (char*)d_ws;
    size_t off = 0;
    auto alloc = [&](size_t bytes) -> void* {
        void* p = ws + off;
        off = (off + bytes + 255) & ~(size_t)255;
        return p;
    };
    float* deg       = (float*)alloc((size_t)N * 4);           // 80 KB
    float* nrm       = (float*)alloc((size_t)E * 4);           // 640 KB
    int*   cnt       = (int*)alloc((size_t)N * 4);
    int*   row_start = (int*)alloc((size_t)(N + 1) * 4);
    int*   cursor    = (int*)alloc((size_t)N * 4);
    int*   csr       = (int*)alloc((size_t)E * 4);             // 640 KB
    float* aggNF     = (float*)alloc((size_t)N * FTEXT * 4);   // 24 MB
    float* x         = (float*)alloc((size_t)N * HIDDIM * 4);  // 82 MB
    float* Z         = (float*)alloc((size_t)HIDDIM * BQ * 4); // 256 KB
    float* Y         = (float*)alloc((size_t)N * BQ * 4);      // 5.1 MB
    float* cvec      = (float*)alloc((size_t)BQ * 4);
    // total ~113 MB

    hipMemsetAsync(deg, 0, (size_t)N * 4, stream);
    hipMemsetAsync(cnt, 0, (size_t)N * 4, stream);
    hipMemsetAsync(cursor, 0, (size_t)N * 4, stream);

    int eb = (E + 255) / 256;
    degcnt_kernel<<<eb, 256, 0, stream>>>(edge_dst, edge_weight, deg, cnt, E);
    norm_kernel<<<eb, 256, 0, stream>>>(edge_src, edge_dst, edge_weight, deg, nrm, E);
    scan_kernel<<<1, 256, 0, stream>>>(cnt, row_start, N);
    fill_kernel<<<eb, 256, 0, stream>>>(edge_dst, row_start, cursor, csr, E);

    // aggNF = A @ node_features   [N x 300]
    aggnf_kernel<<<N, 128, 0, stream>>>(node_features, row_start, csr, edge_src, nrm,
                                        aggNF, FTEXT / 4);
    // x = leaky(aggNF @ W1 + b1)   [N x 1024]
    gemm_tile<0, 1><<<dim3(HIDDIM / TS, (N + TS - 1) / TS), 256, 0, stream>>>(
        aggNF, W1, b1, x, N, HIDDIM, FTEXT);
    // Z = W2 @ img^T   [1024 x 64]
    gemm_tile<1, 0><<<dim3((BQ + TS - 1) / TS, HIDDIM / TS), 256, 0, stream>>>(
        W2, img_feat, nullptr, Z, HIDDIM, BQ, OUTDIM);
    // Y = x @ Z   [N x 64]
    gemm_tile<0, 0><<<dim3((BQ + TS - 1) / TS, (N + TS - 1) / TS), 256, 0, stream>>>(
        x, Z, nullptr, Y, N, BQ, HIDDIM);
    // cvec[b] = img[b,:] . b2
    cvec_kernel<<<BQ, 64, 0, stream>>>(img_feat, b2, cvec, OUTDIM);
    // out[b,d] = sum nrm*Y[src,b] + cvec[b]
    outagg_kernel<<<N, 64, 0, stream>>>(Y, row_start, csr, edge_src, nrm, cvec, out, N);
}

// Round 3
// 572.999 us; speedup vs baseline: 1.4813x; 1.4813x over previous
//
#include <hip/hip_runtime.h>
#include <hip/hip_bf16.h>

#define NNODES 20000
#define NEDGES 160000
#define BQ     64
#define FTEXT  300
#define KPAD1  320          // FTEXT padded to multiple of 32
#define HIDDIM 1024
#define OUTDIM 1664

typedef __attribute__((ext_vector_type(8))) short short8;
typedef __attribute__((ext_vector_type(4))) float floatx4;

__device__ inline unsigned short f2bf(float f) {
    union { float f; unsigned int u; } v; v.f = f;
    unsigned int r = v.u + 0x7FFF + ((v.u >> 16) & 1);   // RNE
    return (unsigned short)(r >> 16);
}

// ---------------- degree + count ----------------
__global__ void degcnt_kernel(const int* __restrict__ dst, const float* __restrict__ w,
                              float* __restrict__ deg, int* __restrict__ cnt, int E) {
    int e = blockIdx.x * blockDim.x + threadIdx.x;
    if (e < E) {
        int d = dst[e];
        atomicAdd(&deg[d], w[e]);
        atomicAdd(&cnt[d], 1);
    }
}

__global__ void norm_kernel(const int* __restrict__ src, const int* __restrict__ dst,
                            const float* __restrict__ w, const float* __restrict__ deg,
                            float* __restrict__ nrm, int E) {
    int e = blockIdx.x * blockDim.x + threadIdx.x;
    if (e < E) {
        float ds = deg[src[e]], dd = deg[dst[e]];
        float is = ds > 0.f ? rsqrtf(ds) : 0.f;
        float id = dd > 0.f ? rsqrtf(dd) : 0.f;
        nrm[e] = is * w[e] * id;
    }
}

// ---------------- CSR build ----------------
__global__ void scan_kernel(const int* __restrict__ cnt, int* __restrict__ row_start, int N) {
    __shared__ int partial[256];
    int t = threadIdx.x;
    int chunk = (N + 255) / 256;
    int begin = t * chunk;
    int end = begin + chunk; if (end > N) end = N;
    int s = 0;
    for (int i = begin; i < end; i++) s += cnt[i];
    partial[t] = s;
    __syncthreads();
    for (int off = 1; off < 256; off <<= 1) {
        int v = (t >= off) ? partial[t - off] : 0;
        __syncthreads();
        partial[t] += v;
        __syncthreads();
    }
    int base = (t == 0) ? 0 : partial[t - 1];
    int run = base;
    for (int i = begin; i < end; i++) { row_start[i] = run; run += cnt[i]; }
    if (t == 255) row_start[N] = partial[255];
}

__global__ void fill_kernel(const int* __restrict__ dst, const int* __restrict__ row_start,
                            int* __restrict__ cursor, int* __restrict__ csr, int E) {
    int e = blockIdx.x * blockDim.x + threadIdx.x;
    if (e < E) {
        int d = dst[e];
        int pos = atomicAdd(&cursor[d], 1);
        csr[row_start[d] + pos] = e;
    }
}

// ---------------- aggNF[d, 0:320] (bf16, zero-padded) = sum nrm[e]*nf[src[e],:] ----
__global__ __launch_bounds__(128) void aggnf_kernel(const float* __restrict__ nf,
        const int* __restrict__ row_start, const int* __restrict__ csr,
        const int* __restrict__ src, const float* __restrict__ nrm,
        unsigned short* __restrict__ out) {
    int d = blockIdx.x;
    int t = threadIdx.x;
    int s0 = row_start[d], s1 = row_start[d + 1];
    unsigned short* orow = out + (long)d * KPAD1;
    for (int f4 = t; f4 < 75; f4 += 128) {
        float4 acc = make_float4(0.f, 0.f, 0.f, 0.f);
        for (int idx = s0; idx < s1; idx++) {
            int e = csr[idx];
            float w = nrm[e];
            float4 hv = ((const float4*)(nf + (long)src[e] * FTEXT))[f4];
            acc.x += hv.x * w; acc.y += hv.y * w; acc.z += hv.z * w; acc.w += hv.w * w;
        }
        ushort4 o;
        o.x = f2bf(acc.x); o.y = f2bf(acc.y); o.z = f2bf(acc.z); o.w = f2bf(acc.w);
        ((ushort4*)orow)[f4] = o;
    }
    if (t < 5) {  // zero pad k=300..319
        ushort4 z; z.x = z.y = z.z = z.w = 0;
        ((ushort4*)(orow + 300))[t] = z;
    }
}

// ---------------- W1bt[n][k] (bf16, k zero-padded to 320) = W1[k][n] ----------
__global__ void cvtW1_kernel(const float* __restrict__ W1, unsigned short* __restrict__ W1bt) {
    int idx = blockIdx.x * 256 + threadIdx.x;
    if (idx >= HIDDIM * KPAD1) return;
    int n = idx / KPAD1, k = idx % KPAD1;
    float v = (k < FTEXT) ? W1[(long)k * HIDDIM + n] : 0.f;
    W1bt[idx] = f2bf(v);
}

// ---------------- fp32 -> bf16 elementwise ----------------
__global__ void cvt_kernel(const float* __restrict__ in, unsigned short* __restrict__ out, int n) {
    int i = blockIdx.x * 256 + threadIdx.x;
    if (i < n) out[i] = f2bf(in[i]);
}

// ---------------- bf16 MFMA GEMM: C[M x N] = A[M x K] @ B^T, B is [N x K] ------
// Tile 128x64, BK=32, 256 threads = 4 waves, wave w owns rows [32w,32w+32).
// Fragment layouts (verified m89/m120): A/B^T lane: [lane&15][quad*8+j];
// C/D: col=lane&15, row=quad*4+reg.
// EPI: +bias[n], leaky_relu(0.2). OUT_BF16: store bf16. ATOMIC: fp32 atomicAdd (split-K).
template<int EPI, int OUT_BF16, int ATOMIC>
__global__ __launch_bounds__(256) void mfma_gemm(
        const unsigned short* __restrict__ A, const unsigned short* __restrict__ B,
        const float* __restrict__ bias, void* __restrict__ Cv,
        int M, int N, int K, int ldc) {
    __shared__ unsigned short As[128][40];   // +8 pad: row stride 80B breaks bank aliasing
    __shared__ unsigned short Bs[64][40];
    int t = threadIdx.x;
    int m0 = blockIdx.y * 128;
    int n0 = blockIdx.x * 64;
    int klen = K / gridDim.z;
    int kbeg = blockIdx.z * klen;
    int wave = t >> 6, lane = t & 63;
    int lm = lane & 15, lq = lane >> 4;
    floatx4 acc[2][4] = {};
    for (int k0 = kbeg; k0 < kbeg + klen; k0 += 32) {
        #pragma unroll
        for (int p = 0; p < 2; p++) {            // A tile: 128 rows x 32k
            int idx = p * 256 + t;
            int r = idx >> 2, c8 = (idx & 3) * 8;
            uint4 v = make_uint4(0, 0, 0, 0);
            int gm = m0 + r;
            if (gm < M) v = *(const uint4*)(A + (long)gm * K + k0 + c8);
            *(uint4*)&As[r][c8] = v;
        }
        {                                        // B tile: 64 rows x 32k
            int r = t >> 2, c8 = (t & 3) * 8;
            uint4 v = *(const uint4*)(B + (long)(n0 + r) * K + k0 + c8);
            *(uint4*)&Bs[r][c8] = v;
        }
        __syncthreads();
        short8 a[2], b[4];
        #pragma unroll
        for (int rt = 0; rt < 2; rt++)
            a[rt] = *(const short8*)&As[wave * 32 + rt * 16 + lm][lq * 8];
        #pragma unroll
        for (int ct = 0; ct < 4; ct++)
            b[ct] = *(const short8*)&Bs[ct * 16 + lm][lq * 8];
        #pragma unroll
        for (int rt = 0; rt < 2; rt++)
            #pragma unroll
            for (int ct = 0; ct < 4; ct++)
                acc[rt][ct] = __builtin_amdgcn_mfma_f32_16x16x32_bf16(
                    a[rt], b[ct], acc[rt][ct], 0, 0, 0);
        __syncthreads();
    }
    #pragma unroll
    for (int rt = 0; rt < 2; rt++) {
        #pragma unroll
        for (int r = 0; r < 4; r++) {
            int gm = m0 + wave * 32 + rt * 16 + lq * 4 + r;
            if (gm >= M) continue;
            #pragma unroll
            for (int ct = 0; ct < 4; ct++) {
                int gn = n0 + ct * 16 + lm;
                float v = acc[rt][ct][r];
                if (EPI) { v += bias[gn]; v = v >= 0.f ? v : 0.2f * v; }
                if (OUT_BF16)      ((unsigned short*)Cv)[(long)gm * ldc + gn] = f2bf(v);
                else if (ATOMIC)   atomicAdd((float*)Cv + (long)gm * ldc + gn, v);
                else               ((float*)Cv)[(long)gm * ldc + gn] = v;
            }
        }
    }
}

// ---------------- fp32 tiled GEMM (kept for Zt = img @ W2^T, tiny) ------------
#define TS 64
#define KS 16
template<int BT>
__global__ __launch_bounds__(256) void gemm_tile(const float* __restrict__ A,
        const float* __restrict__ B, float* __restrict__ C, int M, int N, int K) {
    __shared__ float As[KS][TS + 4];
    __shared__ float Bs[KS][TS + 4];
    int t = threadIdx.x;
    int m0 = blockIdx.y * TS;
    int n0 = blockIdx.x * TS;
    int tx = t % 16, ty = t / 16;
    float acc[4][4] = {};
    for (int k0 = 0; k0 < K; k0 += KS) {
        #pragma unroll
        for (int i = 0; i < 4; i++) {
            int idx = i * 256 + t;
            int kk = idx % KS;
            int m = idx / KS;
            float v = 0.f;
            int gm = m0 + m, gk = k0 + kk;
            if (gm < M && gk < K) v = A[(long)gm * K + gk];
            As[kk][m] = v;
        }
        #pragma unroll
        for (int i = 0; i < 4; i++) {
            int idx = i * 256 + t;
            float v = 0.f;
            if (BT) {
                int kk = idx % KS;
                int n = idx / KS;
                int gn = n0 + n, gk = k0 + kk;
                if (gn < N && gk < K) v = B[(long)gn * K + gk];
                Bs[kk][n] = v;
            } else {
                int n = idx % TS;
                int kk = idx / TS;
                int gn = n0 + n, gk = k0 + kk;
                if (gn < N && gk < K) v = B[(long)gk * N + gn];
                Bs[kk][n] = v;
            }
        }
        __syncthreads();
        #pragma unroll
        for (int kk = 0; kk < KS; kk++) {
            float a[4], b[4];
            #pragma unroll
            for (int i = 0; i < 4; i++) a[i] = As[kk][ty * 4 + i];
            #pragma unroll
            for (int j = 0; j < 4; j++) b[j] = Bs[kk][tx * 4 + j];
            #pragma unroll
            for (int i = 0; i < 4; i++)
                #pragma unroll
                for (int j = 0; j < 4; j++)
                    acc[i][j] += a[i] * b[j];
        }
        __syncthreads();
    }
    #pragma unroll
    for (int i = 0; i < 4; i++) {
        int gm = m0 + ty * 4 + i;
        if (gm >= M) continue;
        #pragma unroll
        for (int j = 0; j < 4; j++) {
            int gn = n0 + tx * 4 + j;
            if (gn < N) C[(long)gm * N + gn] = acc[i][j];
        }
    }
}

// ---------------- c[b] = img[b,:] . b2 ----------------
__global__ __launch_bounds__(64) void cvec_kernel(const float* __restrict__ img,
        const float* __restrict__ b2, float* __restrict__ c, int K) {
    int b = blockIdx.x;
    int l = threadIdx.x;
    float v = 0.f;
    for (int f = l; f < K; f += 64) v += img[(long)b * K + f] * b2[f];
    for (int off = 32; off > 0; off >>= 1) v += __shfl_down(v, off);
    if (l == 0) c[b] = v;
}

// ---------------- out[b,d] = sum_{e:dst=d} nrm[e]*Y[src[e],b] + c[b] ----------
// 64-d tile per block; compute lane=b, then LDS transpose for coalesced writes.
__global__ __launch_bounds__(256) void outagg_kernel(const float* __restrict__ Y,
        const int* __restrict__ row_start, const int* __restrict__ csr,
        const int* __restrict__ src, const float* __restrict__ nrm,
        const float* __restrict__ c, float* __restrict__ out, int N) {
    __shared__ float tile[64][65];
    int d0 = blockIdx.x * 64;
    int t = threadIdx.x;
    int wave = t >> 6, lane = t & 63;
    float cb = c[lane];
    for (int i = 0; i < 16; i++) {
        int dl = wave * 16 + i;
        int d = d0 + dl;
        float acc = 0.f;
        if (d < N) {
            int s0 = row_start[d], s1 = row_start[d + 1];
            for (int idx = s0; idx < s1; idx++) {
                int e = csr[idx];
                acc += nrm[e] * Y[(long)src[e] * 64 + lane];
            }
        }
        tile[dl][lane] = acc + cb;
    }
    __syncthreads();
    int dcol = t & 63, bq = t >> 6;
    int d = d0 + dcol;
    if (d < N)
        for (int b = bq; b < 64; b += 4)
            out[(long)b * N + d] = tile[dcol][b];
}

extern "C" void kernel_launch(void* const* d_in, const int* in_sizes, int n_in,
                              void* d_out, int out_size, void* d_ws, size_t ws_size,
                              hipStream_t stream) {
    const float* img_feat      = (const float*)d_in[0];
    const float* node_features = (const float*)d_in[1];
    const int*   edge_src      = (const int*)d_in[2];
    const int*   edge_dst      = (const int*)d_in[3];
    const float* edge_weight   = (const float*)d_in[4];
    const float* W1            = (const float*)d_in[5];
    const float* b1            = (const float*)d_in[6];
    const float* W2            = (const float*)d_in[7];
    const float* b2            = (const float*)d_in[8];
    float* out = (float*)d_out;

    const int N = NNODES, E = NEDGES;

    char* ws = (char*)d_ws;
    size_t off = 0;
    auto alloc = [&](size_t bytes) -> void* {
        void* p = ws + off;
        off = (off + bytes + 255) & ~(size_t)255;
        return p;
    };
    float*          deg       = (float*)alloc((size_t)N * 4);
    float*          nrm       = (float*)alloc((size_t)E * 4);
    int*            cnt       = (int*)alloc((size_t)N * 4);
    int*            row_start = (int*)alloc((size_t)(N + 1) * 4);
    int*            cursor    = (int*)alloc((size_t)N * 4);
    int*            csr       = (int*)alloc((size_t)E * 4);
    unsigned short* aggNF     = (unsigned short*)alloc((size_t)N * KPAD1 * 2);   // 12.8 MB
    unsigned short* W1bt      = (unsigned short*)alloc((size_t)HIDDIM * KPAD1 * 2);
    unsigned short* x         = (unsigned short*)alloc((size_t)N * HIDDIM * 2);  // 41 MB
    float*          Ztf       = (float*)alloc((size_t)BQ * HIDDIM * 4);
    unsigned short* Zt        = (unsigned short*)alloc((size_t)BQ * HIDDIM * 2);
    float*          Y         = (float*)alloc((size_t)N * BQ * 4);               // 5.1 MB
    float*          cvec      = (float*)alloc((size_t)BQ * 4);
    // total ~62 MB

    hipMemsetAsync(deg, 0, (size_t)N * 4, stream);
    hipMemsetAsync(cnt, 0, (size_t)N * 4, stream);
    hipMemsetAsync(cursor, 0, (size_t)N * 4, stream);
    hipMemsetAsync(Y, 0, (size_t)N * BQ * 4, stream);

    int eb = (E + 255) / 256;
    degcnt_kernel<<<eb, 256, 0, stream>>>(edge_dst, edge_weight, deg, cnt, E);
    norm_kernel<<<eb, 256, 0, stream>>>(edge_src, edge_dst, edge_weight, deg, nrm, E);
    scan_kernel<<<1, 256, 0, stream>>>(cnt, row_start, N);
    fill_kernel<<<eb, 256, 0, stream>>>(edge_dst, row_start, cursor, csr, E);

    // W1bt = bf16(W1^T) padded; Ztf = img @ W2^T; Zt = bf16(Ztf)
    cvtW1_kernel<<<(HIDDIM * KPAD1 + 255) / 256, 256, 0, stream>>>(W1, W1bt);
    gemm_tile<1><<<dim3(HIDDIM / TS, 1), 256, 0, stream>>>(img_feat, W2, Ztf, BQ, HIDDIM, OUTDIM);
    cvt_kernel<<<(BQ * HIDDIM + 255) / 256, 256, 0, stream>>>(Ztf, Zt, BQ * HIDDIM);

    // aggNF = bf16(A @ node_features), k-padded
    aggnf_kernel<<<N, 128, 0, stream>>>(node_features, row_start, csr, edge_src, nrm, aggNF);

    // x = bf16(leaky(aggNF @ W1 + b1))   [N x 1024]   (MFMA)
    mfma_gemm<1, 1, 0><<<dim3(HIDDIM / 64, (N + 127) / 128, 1), 256, 0, stream>>>(
        aggNF, W1bt, b1, x, N, HIDDIM, KPAD1, HIDDIM);

    // Y += x @ Zt^T   [N x 64]   (MFMA, split-K=4, fp32 atomic accumulate)
    mfma_gemm<0, 0, 1><<<dim3(1, (N + 127) / 128, 4), 256, 0, stream>>>(
        x, Zt, nullptr, Y, N, BQ, HIDDIM, BQ);

    cvec_kernel<<<BQ, 64, 0, stream>>>(img_feat, b2, cvec, OUTDIM);
    outagg_kernel<<<(N + 63) / 64, 256, 0, stream>>>(Y, row_start, csr, edge_src, nrm,
                                                     cvec, out, N);
}

// Round 4
// 415.890 us; speedup vs baseline: 2.0409x; 1.3778x over previous
//
#include <hip/hip_runtime.h>
#include <hip/hip_bf16.h>

#define NNODES 20000
#define NEDGES 160000
#define BQ     64
#define FTEXT  300
#define KPAD1  320          // FTEXT padded to multiple of 32
#define HIDDIM 1024
#define OUTDIM 1664

typedef __attribute__((ext_vector_type(8))) short short8;
typedef __attribute__((ext_vector_type(4))) float floatx4;

__device__ inline unsigned short f2bf(float f) {
    union { float f; unsigned int u; } v; v.f = f;
    unsigned int r = v.u + 0x7FFF + ((v.u >> 16) & 1);   // RNE
    return (unsigned short)(r >> 16);
}

// ---------------- degree + count ----------------
__global__ void degcnt_kernel(const int* __restrict__ dst, const float* __restrict__ w,
                              float* __restrict__ deg, int* __restrict__ cnt, int E) {
    int e = blockIdx.x * blockDim.x + threadIdx.x;
    if (e < E) {
        int d = dst[e];
        atomicAdd(&deg[d], w[e]);
        atomicAdd(&cnt[d], 1);
    }
}

__global__ void norm_kernel(const int* __restrict__ src, const int* __restrict__ dst,
                            const float* __restrict__ w, const float* __restrict__ deg,
                            float* __restrict__ nrm, int E) {
    int e = blockIdx.x * blockDim.x + threadIdx.x;
    if (e < E) {
        float ds = deg[src[e]], dd = deg[dst[e]];
        float is = ds > 0.f ? rsqrtf(ds) : 0.f;
        float id = dd > 0.f ? rsqrtf(dd) : 0.f;
        nrm[e] = is * w[e] * id;
    }
}

// ---------------- CSR build ----------------
__global__ void scan_kernel(const int* __restrict__ cnt, int* __restrict__ row_start, int N) {
    __shared__ int partial[256];
    int t = threadIdx.x;
    int chunk = (N + 255) / 256;
    int begin = t * chunk;
    int end = begin + chunk; if (end > N) end = N;
    int s = 0;
    for (int i = begin; i < end; i++) s += cnt[i];
    partial[t] = s;
    __syncthreads();
    for (int off = 1; off < 256; off <<= 1) {
        int v = (t >= off) ? partial[t - off] : 0;
        __syncthreads();
        partial[t] += v;
        __syncthreads();
    }
    int base = (t == 0) ? 0 : partial[t - 1];
    int run = base;
    for (int i = begin; i < end; i++) { row_start[i] = run; run += cnt[i]; }
    if (t == 255) row_start[N] = partial[255];
}

__global__ void fill_kernel(const int* __restrict__ dst, const int* __restrict__ row_start,
                            int* __restrict__ cursor, int* __restrict__ csr, int E) {
    int e = blockIdx.x * blockDim.x + threadIdx.x;
    if (e < E) {
        int d = dst[e];
        int pos = atomicAdd(&cursor[d], 1);
        csr[row_start[d] + pos] = e;
    }
}

// ---------------- aggNF[d, 0:320] (bf16, zero-padded) = sum nrm[e]*nf[src[e],:] ----
__global__ __launch_bounds__(128) void aggnf_kernel(const float* __restrict__ nf,
        const int* __restrict__ row_start, const int* __restrict__ csr,
        const int* __restrict__ src, const float* __restrict__ nrm,
        unsigned short* __restrict__ out) {
    int d = blockIdx.x;
    int t = threadIdx.x;
    int s0 = row_start[d], s1 = row_start[d + 1];
    unsigned short* orow = out + (long)d * KPAD1;
    for (int f4 = t; f4 < 75; f4 += 128) {
        float4 acc = make_float4(0.f, 0.f, 0.f, 0.f);
        for (int idx = s0; idx < s1; idx++) {
            int e = csr[idx];
            float w = nrm[e];
            float4 hv = ((const float4*)(nf + (long)src[e] * FTEXT))[f4];
            acc.x += hv.x * w; acc.y += hv.y * w; acc.z += hv.z * w; acc.w += hv.w * w;
        }
        ushort4 o;
        o.x = f2bf(acc.x); o.y = f2bf(acc.y); o.z = f2bf(acc.z); o.w = f2bf(acc.w);
        ((ushort4*)orow)[f4] = o;
    }
    if (t < 5) {  // zero pad k=300..319
        ushort4 z; z.x = z.y = z.z = z.w = 0;
        ((ushort4*)(orow + 300))[t] = z;
    }
}

// ---------------- W1bt[n][k] (bf16, k zero-padded to 320) = W1[k][n] ----------
__global__ void cvtW1_kernel(const float* __restrict__ W1, unsigned short* __restrict__ W1bt) {
    int idx = blockIdx.x * 256 + threadIdx.x;
    if (idx >= HIDDIM * KPAD1) return;
    int n = idx / KPAD1, k = idx % KPAD1;
    float v = (k < FTEXT) ? W1[(long)k * HIDDIM + n] : 0.f;
    W1bt[idx] = f2bf(v);
}

// ---------------- fp32 -> bf16 elementwise ----------------
__global__ void cvt_kernel(const float* __restrict__ in, unsigned short* __restrict__ out, int n) {
    int i = blockIdx.x * 256 + threadIdx.x;
    if (i < n) out[i] = f2bf(in[i]);
}

// ---------------- bf16 MFMA GEMM: C[M x N] = A[M x K] @ B^T, B is [N x K] ------
// Tile 128x64, BK=32, 256 threads = 4 waves, wave w owns rows [32w,32w+32).
// Fragment layouts (verified m89/m120): A/B^T lane: [lane&15][quad*8+j];
// C/D: col=lane&15, row=quad*4+reg.
// EPI: +bias[n], leaky_relu(0.2). OUT_BF16: store bf16. ATOMIC: fp32 atomicAdd (split-K).
template<int EPI, int OUT_BF16, int ATOMIC>
__global__ __launch_bounds__(256) void mfma_gemm(
        const unsigned short* __restrict__ A, const unsigned short* __restrict__ B,
        const float* __restrict__ bias, void* __restrict__ Cv,
        int M, int N, int K, int ldc) {
    __shared__ unsigned short As[128][40];   // +8 pad: row stride 80B breaks bank aliasing
    __shared__ unsigned short Bs[64][40];
    int t = threadIdx.x;
    int m0 = blockIdx.y * 128;
    int n0 = blockIdx.x * 64;
    int klen = K / gridDim.z;
    int kbeg = blockIdx.z * klen;
    int wave = t >> 6, lane = t & 63;
    int lm = lane & 15, lq = lane >> 4;
    floatx4 acc[2][4] = {};
    for (int k0 = kbeg; k0 < kbeg + klen; k0 += 32) {
        #pragma unroll
        for (int p = 0; p < 2; p++) {            // A tile: 128 rows x 32k
            int idx = p * 256 + t;
            int r = idx >> 2, c8 = (idx & 3) * 8;
            uint4 v = make_uint4(0, 0, 0, 0);
            int gm = m0 + r;
            if (gm < M) v = *(const uint4*)(A + (long)gm * K + k0 + c8);
            *(uint4*)&As[r][c8] = v;
        }
        {                                        // B tile: 64 rows x 32k
            int r = t >> 2, c8 = (t & 3) * 8;
            uint4 v = *(const uint4*)(B + (long)(n0 + r) * K + k0 + c8);
            *(uint4*)&Bs[r][c8] = v;
        }
        __syncthreads();
        short8 a[2], b[4];
        #pragma unroll
        for (int rt = 0; rt < 2; rt++)
            a[rt] = *(const short8*)&As[wave * 32 + rt * 16 + lm][lq * 8];
        #pragma unroll
        for (int ct = 0; ct < 4; ct++)
            b[ct] = *(const short8*)&Bs[ct * 16 + lm][lq * 8];
        #pragma unroll
        for (int rt = 0; rt < 2; rt++)
            #pragma unroll
            for (int ct = 0; ct < 4; ct++)
                acc[rt][ct] = __builtin_amdgcn_mfma_f32_16x16x32_bf16(
                    a[rt], b[ct], acc[rt][ct], 0, 0, 0);
        __syncthreads();
    }
    #pragma unroll
    for (int rt = 0; rt < 2; rt++) {
        #pragma unroll
        for (int r = 0; r < 4; r++) {
            int gm = m0 + wave * 32 + rt * 16 + lq * 4 + r;
            if (gm >= M) continue;
            #pragma unroll
            for (int ct = 0; ct < 4; ct++) {
                int gn = n0 + ct * 16 + lm;
                float v = acc[rt][ct][r];
                if (EPI) { v += bias[gn]; v = v >= 0.f ? v : 0.2f * v; }
                if (OUT_BF16)      ((unsigned short*)Cv)[(long)gm * ldc + gn] = f2bf(v);
                else if (ATOMIC)   atomicAdd((float*)Cv + (long)gm * ldc + gn, v);
                else               ((float*)Cv)[(long)gm * ldc + gn] = v;
            }
        }
    }
}

// ---------------- fp32 tiled GEMM with split-K (Zt = img @ W2^T) --------------
// BT=1: C[MxN] = A[MxK] @ B^T, B is [NxK]. gridDim.z splits K; ATOMIC accumulates.
#define TS 64
#define KS 16
template<int BT, int ATOMIC>
__global__ __launch_bounds__(256) void gemm_tile(const float* __restrict__ A,
        const float* __restrict__ B, float* __restrict__ C, int M, int N, int K) {
    __shared__ float As[KS][TS + 4];
    __shared__ float Bs[KS][TS + 4];
    int t = threadIdx.x;
    int m0 = blockIdx.y * TS;
    int n0 = blockIdx.x * TS;
    int klen = K / gridDim.z;
    int kbeg = blockIdx.z * klen;
    int tx = t % 16, ty = t / 16;
    float acc[4][4] = {};
    for (int k0 = kbeg; k0 < kbeg + klen; k0 += KS) {
        #pragma unroll
        for (int i = 0; i < 4; i++) {
            int idx = i * 256 + t;
            int kk = idx % KS;
            int m = idx / KS;
            float v = 0.f;
            int gm = m0 + m, gk = k0 + kk;
            if (gm < M && gk < K) v = A[(long)gm * K + gk];
            As[kk][m] = v;
        }
        #pragma unroll
        for (int i = 0; i < 4; i++) {
            int idx = i * 256 + t;
            float v = 0.f;
            if (BT) {
                int kk = idx % KS;
                int n = idx / KS;
                int gn = n0 + n, gk = k0 + kk;
                if (gn < N && gk < K) v = B[(long)gn * K + gk];
                Bs[kk][n] = v;
            } else {
                int n = idx % TS;
                int kk = idx / TS;
                int gn = n0 + n, gk = k0 + kk;
                if (gn < N && gk < K) v = B[(long)gk * N + gn];
                Bs[kk][n] = v;
            }
        }
        __syncthreads();
        #pragma unroll
        for (int kk = 0; kk < KS; kk++) {
            float a[4], b[4];
            #pragma unroll
            for (int i = 0; i < 4; i++) a[i] = As[kk][ty * 4 + i];
            #pragma unroll
            for (int j = 0; j < 4; j++) b[j] = Bs[kk][tx * 4 + j];
            #pragma unroll
            for (int i = 0; i < 4; i++)
                #pragma unroll
                for (int j = 0; j < 4; j++)
                    acc[i][j] += a[i] * b[j];
        }
        __syncthreads();
    }
    #pragma unroll
    for (int i = 0; i < 4; i++) {
        int gm = m0 + ty * 4 + i;
        if (gm >= M) continue;
        #pragma unroll
        for (int j = 0; j < 4; j++) {
            int gn = n0 + tx * 4 + j;
            if (gn >= N) continue;
            if (ATOMIC) atomicAdd(&C[(long)gm * N + gn], acc[i][j]);
            else        C[(long)gm * N + gn] = acc[i][j];
        }
    }
}

// ---------------- c[b] = img[b,:] . b2 ----------------
__global__ __launch_bounds__(64) void cvec_kernel(const float* __restrict__ img,
        const float* __restrict__ b2, float* __restrict__ c, int K) {
    int b = blockIdx.x;
    int l = threadIdx.x;
    float v = 0.f;
    for (int f = l; f < K; f += 64) v += img[(long)b * K + f] * b2[f];
    for (int off = 32; off > 0; off >>= 1) v += __shfl_down(v, off);
    if (l == 0) c[b] = v;
}

// ---------------- out[b,d] = sum_{e:dst=d} nrm[e]*Y[src[e],b] + c[b] ----------
// 64-d tile per block; compute lane=b, then LDS transpose for coalesced writes.
__global__ __launch_bounds__(256) void outagg_kernel(const float* __restrict__ Y,
        const int* __restrict__ row_start, const int* __restrict__ csr,
        const int* __restrict__ src, const float* __restrict__ nrm,
        const float* __restrict__ c, float* __restrict__ out, int N) {
    __shared__ float tile[64][65];
    int d0 = blockIdx.x * 64;
    int t = threadIdx.x;
    int wave = t >> 6, lane = t & 63;
    float cb = c[lane];
    for (int i = 0; i < 16; i++) {
        int dl = wave * 16 + i;
        int d = d0 + dl;
        float acc = 0.f;
        if (d < N) {
            int s0 = row_start[d], s1 = row_start[d + 1];
            for (int idx = s0; idx < s1; idx++) {
                int e = csr[idx];
                acc += nrm[e] * Y[(long)src[e] * 64 + lane];
            }
        }
        tile[dl][lane] = acc + cb;
    }
    __syncthreads();
    int dcol = t & 63, bq = t >> 6;
    int d = d0 + dcol;
    if (d < N)
        for (int b = bq; b < 64; b += 4)
            out[(long)b * N + d] = tile[dcol][b];
}

extern "C" void kernel_launch(void* const* d_in, const int* in_sizes, int n_in,
                              void* d_out, int out_size, void* d_ws, size_t ws_size,
                              hipStream_t stream) {
    const float* img_feat      = (const float*)d_in[0];
    const float* node_features = (const float*)d_in[1];
    const int*   edge_src      = (const int*)d_in[2];
    const int*   edge_dst      = (const int*)d_in[3];
    const float* edge_weight   = (const float*)d_in[4];
    const float* W1            = (const float*)d_in[5];
    const float* b1            = (const float*)d_in[6];
    const float* W2            = (const float*)d_in[7];
    const float* b2            = (const float*)d_in[8];
    float* out = (float*)d_out;

    const int N = NNODES, E = NEDGES;

    char* ws = (char*)d_ws;
    size_t off = 0;
    auto alloc = [&](size_t bytes) -> void* {
        void* p = ws + off;
        off = (off + bytes + 255) & ~(size_t)255;
        return p;
    };
    float*          deg       = (float*)alloc((size_t)N * 4);
    float*          nrm       = (float*)alloc((size_t)E * 4);
    int*            cnt       = (int*)alloc((size_t)N * 4);
    int*            row_start = (int*)alloc((size_t)(N + 1) * 4);
    int*            cursor    = (int*)alloc((size_t)N * 4);
    int*            csr       = (int*)alloc((size_t)E * 4);
    unsigned short* aggNF     = (unsigned short*)alloc((size_t)N * KPAD1 * 2);   // 12.8 MB
    unsigned short* W1bt      = (unsigned short*)alloc((size_t)HIDDIM * KPAD1 * 2);
    unsigned short* x         = (unsigned short*)alloc((size_t)N * HIDDIM * 2);  // 41 MB
    float*          Ztf       = (float*)alloc((size_t)BQ * HIDDIM * 4);
    unsigned short* Zt        = (unsigned short*)alloc((size_t)BQ * HIDDIM * 2);
    float*          Y         = (float*)alloc((size_t)N * BQ * 4);               // 5.1 MB
    float*          cvec      = (float*)alloc((size_t)BQ * 4);
    // total ~62 MB

    hipMemsetAsync(deg, 0, (size_t)N * 4, stream);
    hipMemsetAsync(cnt, 0, (size_t)N * 4, stream);
    hipMemsetAsync(cursor, 0, (size_t)N * 4, stream);
    hipMemsetAsync(Y, 0, (size_t)N * BQ * 4, stream);
    hipMemsetAsync(Ztf, 0, (size_t)BQ * HIDDIM * 4, stream);

    int eb = (E + 255) / 256;
    degcnt_kernel<<<eb, 256, 0, stream>>>(edge_dst, edge_weight, deg, cnt, E);
    norm_kernel<<<eb, 256, 0, stream>>>(edge_src, edge_dst, edge_weight, deg, nrm, E);
    scan_kernel<<<1, 256, 0, stream>>>(cnt, row_start, N);
    fill_kernel<<<eb, 256, 0, stream>>>(edge_dst, row_start, cursor, csr, E);

    // W1bt = bf16(W1^T) padded; Ztf = img @ W2^T (split-K=26); Zt = bf16(Ztf)
    cvtW1_kernel<<<(HIDDIM * KPAD1 + 255) / 256, 256, 0, stream>>>(W1, W1bt);
    gemm_tile<1, 1><<<dim3(HIDDIM / TS, 1, 26), 256, 0, stream>>>(
        img_feat, W2, Ztf, BQ, HIDDIM, OUTDIM);
    cvt_kernel<<<(BQ * HIDDIM + 255) / 256, 256, 0, stream>>>(Ztf, Zt, BQ * HIDDIM);

    // aggNF = bf16(A @ node_features), k-padded
    aggnf_kernel<<<N, 128, 0, stream>>>(node_features, row_start, csr, edge_src, nrm, aggNF);

    // x = bf16(leaky(aggNF @ W1 + b1))   [N x 1024]   (MFMA)
    mfma_gemm<1, 1, 0><<<dim3(HIDDIM / 64, (N + 127) / 128, 1), 256, 0, stream>>>(
        aggNF, W1bt, b1, x, N, HIDDIM, KPAD1, HIDDIM);

    // Y += x @ Zt^T   [N x 64]   (MFMA, split-K=4, fp32 atomic accumulate)
    mfma_gemm<0, 0, 1><<<dim3(1, (N + 127) / 128, 4), 256, 0, stream>>>(
        x, Zt, nullptr, Y, N, BQ, HIDDIM, BQ);

    cvec_kernel<<<BQ, 64, 0, stream>>>(img_feat, b2, cvec, OUTDIM);
    outagg_kernel<<<(N + 63) / 64, 256, 0, stream>>>(Y, row_start, csr, edge_src, nrm,
                                                     cvec, out, N);
}

// Round 5
// 324.828 us; speedup vs baseline: 2.6131x; 1.2803x over previous
//
#include <hip/hip_runtime.h>
#include <hip/hip_bf16.h>

#define NNODES 20000
#define NEDGES 160000
#define BQ     64
#define FTEXT  300
#define KPAD1  320          // FTEXT padded to multiple of 32
#define HIDDIM 1024
#define OUTDIM 1664

typedef __attribute__((ext_vector_type(8))) short short8;
typedef __attribute__((ext_vector_type(4))) float floatx4;

__device__ inline unsigned short f2bf(float f) {
    union { float f; unsigned int u; } v; v.f = f;
    unsigned int r = v.u + 0x7FFF + ((v.u >> 16) & 1);   // RNE
    return (unsigned short)(r >> 16);
}

// ---------------- degree + count ----------------
__global__ void degcnt_kernel(const int* __restrict__ dst, const float* __restrict__ w,
                              float* __restrict__ deg, int* __restrict__ cnt, int E) {
    int e = blockIdx.x * blockDim.x + threadIdx.x;
    if (e < E) {
        int d = dst[e];
        atomicAdd(&deg[d], w[e]);
        atomicAdd(&cnt[d], 1);
    }
}

__global__ void norm_kernel(const int* __restrict__ src, const int* __restrict__ dst,
                            const float* __restrict__ w, const float* __restrict__ deg,
                            float* __restrict__ nrm, int E) {
    int e = blockIdx.x * blockDim.x + threadIdx.x;
    if (e < E) {
        float ds = deg[src[e]], dd = deg[dst[e]];
        float is = ds > 0.f ? rsqrtf(ds) : 0.f;
        float id = dd > 0.f ? rsqrtf(dd) : 0.f;
        nrm[e] = is * w[e] * id;
    }
}

// ---------------- CSR build ----------------
__global__ void scan_kernel(const int* __restrict__ cnt, int* __restrict__ row_start, int N) {
    __shared__ int partial[256];
    int t = threadIdx.x;
    int chunk = (N + 255) / 256;
    int begin = t * chunk;
    int end = begin + chunk; if (end > N) end = N;
    int s = 0;
    for (int i = begin; i < end; i++) s += cnt[i];
    partial[t] = s;
    __syncthreads();
    for (int off = 1; off < 256; off <<= 1) {
        int v = (t >= off) ? partial[t - off] : 0;
        __syncthreads();
        partial[t] += v;
        __syncthreads();
    }
    int base = (t == 0) ? 0 : partial[t - 1];
    int run = base;
    for (int i = begin; i < end; i++) { row_start[i] = run; run += cnt[i]; }
    if (t == 255) row_start[N] = partial[255];
}

// dst-sorted edge arrays: src_s[pos], wnrm_s[pos] for pos in [row_start[d], row_start[d+1])
__global__ void fill_kernel(const int* __restrict__ dst, const int* __restrict__ src,
                            const float* __restrict__ nrm, const int* __restrict__ row_start,
                            int* __restrict__ cursor, int* __restrict__ src_s,
                            float* __restrict__ wnrm_s, int E) {
    int e = blockIdx.x * blockDim.x + threadIdx.x;
    if (e < E) {
        int d = dst[e];
        int pos = row_start[d] + atomicAdd(&cursor[d], 1);
        src_s[pos] = src[e];
        wnrm_s[pos] = nrm[e];
    }
}

// ---------------- aggNF[d, 0:320] (bf16, zero-padded) = sum w*nf[src,:] --------
__global__ __launch_bounds__(128) void aggnf_kernel(const float* __restrict__ nf,
        const int* __restrict__ row_start, const int* __restrict__ src_s,
        const float* __restrict__ wnrm_s, unsigned short* __restrict__ out) {
    int d = blockIdx.x;
    int t = threadIdx.x;
    int s0 = row_start[d], s1 = row_start[d + 1];
    unsigned short* orow = out + (long)d * KPAD1;
    for (int f4 = t; f4 < 75; f4 += 128) {
        float4 acc = make_float4(0.f, 0.f, 0.f, 0.f);
        for (int idx = s0; idx < s1; idx++) {
            float w = wnrm_s[idx];
            float4 hv = ((const float4*)(nf + (long)src_s[idx] * FTEXT))[f4];
            acc.x += hv.x * w; acc.y += hv.y * w; acc.z += hv.z * w; acc.w += hv.w * w;
        }
        ushort4 o;
        o.x = f2bf(acc.x); o.y = f2bf(acc.y); o.z = f2bf(acc.z); o.w = f2bf(acc.w);
        ((ushort4*)orow)[f4] = o;
    }
    if (t < 5) {  // zero pad k=300..319
        ushort4 z; z.x = z.y = z.z = z.w = 0;
        ((ushort4*)(orow + 300))[t] = z;
    }
}

// ---------------- W1bt[n][k] (bf16, k zero-padded to 320) = W1[k][n] ----------
__global__ void cvtW1_kernel(const float* __restrict__ W1, unsigned short* __restrict__ W1bt) {
    int idx = blockIdx.x * 256 + threadIdx.x;
    if (idx >= HIDDIM * KPAD1) return;
    int n = idx / KPAD1, k = idx % KPAD1;
    float v = (k < FTEXT) ? W1[(long)k * HIDDIM + n] : 0.f;
    W1bt[idx] = f2bf(v);
}

// ---------------- fp32 -> bf16 elementwise ----------------
__global__ void cvt_kernel(const float* __restrict__ in, unsigned short* __restrict__ out, int n) {
    int i = blockIdx.x * 256 + threadIdx.x;
    if (i < n) out[i] = f2bf(in[i]);
}

// ---------------- bf16 MFMA GEMM: C[M x N] = A[M x K] @ B^T, B is [N x K] ------
// Tile 128x64, BK=32, 256 threads = 4 waves, wave w owns rows [32w,32w+32).
// A/B^T frag: [lane&15][quad*8+j]; C/D: col=lane&15, row=quad*4+reg.
template<int EPI, int OUT_BF16, int ATOMIC>
__global__ __launch_bounds__(256) void mfma_gemm(
        const unsigned short* __restrict__ A, const unsigned short* __restrict__ B,
        const float* __restrict__ bias, void* __restrict__ Cv,
        int M, int N, int K, int ldc) {
    __shared__ unsigned short As[128][40];
    __shared__ unsigned short Bs[64][40];
    int t = threadIdx.x;
    int m0 = blockIdx.y * 128;
    int n0 = blockIdx.x * 64;
    int klen = K / gridDim.z;
    int kbeg = blockIdx.z * klen;
    int wave = t >> 6, lane = t & 63;
    int lm = lane & 15, lq = lane >> 4;
    floatx4 acc[2][4] = {};
    for (int k0 = kbeg; k0 < kbeg + klen; k0 += 32) {
        #pragma unroll
        for (int p = 0; p < 2; p++) {
            int idx = p * 256 + t;
            int r = idx >> 2, c8 = (idx & 3) * 8;
            uint4 v = make_uint4(0, 0, 0, 0);
            int gm = m0 + r;
            if (gm < M) v = *(const uint4*)(A + (long)gm * K + k0 + c8);
            *(uint4*)&As[r][c8] = v;
        }
        {
            int r = t >> 2, c8 = (t & 3) * 8;
            uint4 v = *(const uint4*)(B + (long)(n0 + r) * K + k0 + c8);
            *(uint4*)&Bs[r][c8] = v;
        }
        __syncthreads();
        short8 a[2], b[4];
        #pragma unroll
        for (int rt = 0; rt < 2; rt++)
            a[rt] = *(const short8*)&As[wave * 32 + rt * 16 + lm][lq * 8];
        #pragma unroll
        for (int ct = 0; ct < 4; ct++)
            b[ct] = *(const short8*)&Bs[ct * 16 + lm][lq * 8];
        #pragma unroll
        for (int rt = 0; rt < 2; rt++)
            #pragma unroll
            for (int ct = 0; ct < 4; ct++)
                acc[rt][ct] = __builtin_amdgcn_mfma_f32_16x16x32_bf16(
                    a[rt], b[ct], acc[rt][ct], 0, 0, 0);
        __syncthreads();
    }
    #pragma unroll
    for (int rt = 0; rt < 2; rt++) {
        #pragma unroll
        for (int r = 0; r < 4; r++) {
            int gm = m0 + wave * 32 + rt * 16 + lq * 4 + r;
            if (gm >= M) continue;
            #pragma unroll
            for (int ct = 0; ct < 4; ct++) {
                int gn = n0 + ct * 16 + lm;
                float v = acc[rt][ct][r];
                if (EPI) { v += bias[gn]; v = v >= 0.f ? v : 0.2f * v; }
                if (OUT_BF16)      ((unsigned short*)Cv)[(long)gm * ldc + gn] = f2bf(v);
                else if (ATOMIC)   atomicAdd((float*)Cv + (long)gm * ldc + gn, v);
                else               ((float*)Cv)[(long)gm * ldc + gn] = v;
            }
        }
    }
}

// ---------------- fp32 tiled GEMM with split-K (Zt = img @ W2^T) --------------
#define TS 64
#define KS 16
template<int BT, int ATOMIC>
__global__ __launch_bounds__(256) void gemm_tile(const float* __restrict__ A,
        const float* __restrict__ B, float* __restrict__ C, int M, int N, int K) {
    __shared__ float As[KS][TS + 4];
    __shared__ float Bs[KS][TS + 4];
    int t = threadIdx.x;
    int m0 = blockIdx.y * TS;
    int n0 = blockIdx.x * TS;
    int klen = K / gridDim.z;
    int kbeg = blockIdx.z * klen;
    int tx = t % 16, ty = t / 16;
    float acc[4][4] = {};
    for (int k0 = kbeg; k0 < kbeg + klen; k0 += KS) {
        #pragma unroll
        for (int i = 0; i < 4; i++) {
            int idx = i * 256 + t;
            int kk = idx % KS;
            int m = idx / KS;
            float v = 0.f;
            int gm = m0 + m, gk = k0 + kk;
            if (gm < M && gk < K) v = A[(long)gm * K + gk];
            As[kk][m] = v;
        }
        #pragma unroll
        for (int i = 0; i < 4; i++) {
            int idx = i * 256 + t;
            float v = 0.f;
            if (BT) {
                int kk = idx % KS;
                int n = idx / KS;
                int gn = n0 + n, gk = k0 + kk;
                if (gn < N && gk < K) v = B[(long)gn * K + gk];
                Bs[kk][n] = v;
            } else {
                int n = idx % TS;
                int kk = idx / TS;
                int gn = n0 + n, gk = k0 + kk;
                if (gn < N && gk < K) v = B[(long)gk * N + gn];
                Bs[kk][n] = v;
            }
        }
        __syncthreads();
        #pragma unroll
        for (int kk = 0; kk < KS; kk++) {
            float a[4], b[4];
            #pragma unroll
            for (int i = 0; i < 4; i++) a[i] = As[kk][ty * 4 + i];
            #pragma unroll
            for (int j = 0; j < 4; j++) b[j] = Bs[kk][tx * 4 + j];
            #pragma unroll
            for (int i = 0; i < 4; i++)
                #pragma unroll
                for (int j = 0; j < 4; j++)
                    acc[i][j] += a[i] * b[j];
        }
        __syncthreads();
    }
    #pragma unroll
    for (int i = 0; i < 4; i++) {
        int gm = m0 + ty * 4 + i;
        if (gm >= M) continue;
        #pragma unroll
        for (int j = 0; j < 4; j++) {
            int gn = n0 + tx * 4 + j;
            if (gn >= N) continue;
            if (ATOMIC) atomicAdd(&C[(long)gm * N + gn], acc[i][j]);
            else        C[(long)gm * N + gn] = acc[i][j];
        }
    }
}

// ---------------- c[b] = img[b,:] . b2 ----------------
__global__ __launch_bounds__(64) void cvec_kernel(const float* __restrict__ img,
        const float* __restrict__ b2, float* __restrict__ c, int K) {
    int b = blockIdx.x;
    int l = threadIdx.x;
    float v = 0.f;
    for (int f = l; f < K; f += 64) v += img[(long)b * K + f] * b2[f];
    for (int off = 32; off > 0; off >>= 1) v += __shfl_down(v, off);
    if (l == 0) c[b] = v;
}

// ---------------- out[b,d] = sum_{e:dst=d} w*Y[src,b] + c[b] ------------------
// one WAVE per dst node (4 nodes/block, 5000 blocks); lane = b.
// Software-pipelined edge loop (scalar edge data overlaps Y gather latency).
__global__ __launch_bounds__(256) void outagg_kernel(const float* __restrict__ Y,
        const int* __restrict__ row_start, const int* __restrict__ src_s,
        const float* __restrict__ wnrm_s, const float* __restrict__ c,
        float* __restrict__ out, int N) {
    __shared__ float tile[4][68];
    int d0 = blockIdx.x * 4;
    int t = threadIdx.x;
    int wave = t >> 6, lane = t & 63;
    int d = d0 + wave;
    int s0 = row_start[d], s1 = row_start[d + 1];
    float acc = 0.f;
    int scur = 0; float wcur = 0.f;
    if (s0 < s1) { scur = src_s[s0]; wcur = wnrm_s[s0]; }
    for (int idx = s0; idx < s1; idx++) {
        int snext = 0; float wnext = 0.f;
        if (idx + 1 < s1) { snext = src_s[idx + 1]; wnext = wnrm_s[idx + 1]; }
        acc += wcur * Y[(long)scur * 64 + lane];
        scur = snext; wcur = wnext;
    }
    tile[wave][lane] = acc + c[lane];
    __syncthreads();
    int b = t >> 2, j = t & 3;
    out[(long)b * N + d0 + j] = tile[j][b];
}

extern "C" void kernel_launch(void* const* d_in, const int* in_sizes, int n_in,
                              void* d_out, int out_size, void* d_ws, size_t ws_size,
                              hipStream_t stream) {
    const float* img_feat      = (const float*)d_in[0];
    const float* node_features = (const float*)d_in[1];
    const int*   edge_src      = (const int*)d_in[2];
    const int*   edge_dst      = (const int*)d_in[3];
    const float* edge_weight   = (const float*)d_in[4];
    const float* W1            = (const float*)d_in[5];
    const float* b1            = (const float*)d_in[6];
    const float* W2            = (const float*)d_in[7];
    const float* b2            = (const float*)d_in[8];
    float* out = (float*)d_out;

    const int N = NNODES, E = NEDGES;

    char* ws = (char*)d_ws;
    size_t off = 0;
    auto alloc = [&](size_t bytes) -> void* {
        void* p = ws + off;
        off = (off + bytes + 255) & ~(size_t)255;
        return p;
    };
    float*          deg       = (float*)alloc((size_t)N * 4);
    float*          nrm       = (float*)alloc((size_t)E * 4);
    int*            cnt       = (int*)alloc((size_t)N * 4);
    int*            row_start = (int*)alloc((size_t)(N + 1) * 4);
    int*            cursor    = (int*)alloc((size_t)N * 4);
    int*            src_s     = (int*)alloc((size_t)E * 4);
    float*          wnrm_s    = (float*)alloc((size_t)E * 4);
    unsigned short* aggNF     = (unsigned short*)alloc((size_t)N * KPAD1 * 2);   // 12.8 MB
    unsigned short* W1bt      = (unsigned short*)alloc((size_t)HIDDIM * KPAD1 * 2);
    unsigned short* x         = (unsigned short*)alloc((size_t)N * HIDDIM * 2);  // 41 MB
    float*          Ztf       = (float*)alloc((size_t)BQ * HIDDIM * 4);
    unsigned short* Zt        = (unsigned short*)alloc((size_t)BQ * HIDDIM * 2);
    float*          Y         = (float*)alloc((size_t)N * BQ * 4);               // 5.1 MB
    float*          cvec      = (float*)alloc((size_t)BQ * 4);

    hipMemsetAsync(deg, 0, (size_t)N * 4, stream);
    hipMemsetAsync(cnt, 0, (size_t)N * 4, stream);
    hipMemsetAsync(cursor, 0, (size_t)N * 4, stream);
    hipMemsetAsync(Y, 0, (size_t)N * BQ * 4, stream);
    hipMemsetAsync(Ztf, 0, (size_t)BQ * HIDDIM * 4, stream);

    int eb = (E + 255) / 256;
    degcnt_kernel<<<eb, 256, 0, stream>>>(edge_dst, edge_weight, deg, cnt, E);
    norm_kernel<<<eb, 256, 0, stream>>>(edge_src, edge_dst, edge_weight, deg, nrm, E);
    scan_kernel<<<1, 256, 0, stream>>>(cnt, row_start, N);
    fill_kernel<<<eb, 256, 0, stream>>>(edge_dst, edge_src, nrm, row_start, cursor,
                                        src_s, wnrm_s, E);

    // W1bt = bf16(W1^T) padded; Ztf = img @ W2^T (split-K=26); Zt = bf16(Ztf)
    cvtW1_kernel<<<(HIDDIM * KPAD1 + 255) / 256, 256, 0, stream>>>(W1, W1bt);
    gemm_tile<1, 1><<<dim3(HIDDIM / TS, 1, 26), 256, 0, stream>>>(
        img_feat, W2, Ztf, BQ, HIDDIM, OUTDIM);
    cvt_kernel<<<(BQ * HIDDIM + 255) / 256, 256, 0, stream>>>(Ztf, Zt, BQ * HIDDIM);

    // aggNF = bf16(A @ node_features), k-padded
    aggnf_kernel<<<N, 128, 0, stream>>>(node_features, row_start, src_s, wnrm_s, aggNF);

    // x = bf16(leaky(aggNF @ W1 + b1))   [N x 1024]   (MFMA)
    mfma_gemm<1, 1, 0><<<dim3(HIDDIM / 64, (N + 127) / 128, 1), 256, 0, stream>>>(
        aggNF, W1bt, b1, x, N, HIDDIM, KPAD1, HIDDIM);

    // Y += x @ Zt^T   [N x 64]   (MFMA, split-K=4, fp32 atomic accumulate)
    mfma_gemm<0, 0, 1><<<dim3(1, (N + 127) / 128, 4), 256, 0, stream>>>(
        x, Zt, nullptr, Y, N, BQ, HIDDIM, BQ);

    cvec_kernel<<<BQ, 64, 0, stream>>>(img_feat, b2, cvec, OUTDIM);
    outagg_kernel<<<N / 4, 256, 0, stream>>>(Y, row_start, src_s, wnrm_s, cvec, out, N);
}

// Round 6
// 290.511 us; speedup vs baseline: 2.9217x; 1.1181x over previous
//
#include <hip/hip_runtime.h>
#include <hip/hip_bf16.h>

#define NNODES 20000
#define NEDGES 160000
#define BQ     64
#define FTEXT  300
#define KPAD1  320          // FTEXT padded to multiple of 32
#define HIDDIM 1024
#define OUTDIM 1664

typedef __attribute__((ext_vector_type(8))) short short8;
typedef __attribute__((ext_vector_type(4))) float floatx4;

__device__ inline unsigned short f2bf(float f) {
    union { float f; unsigned int u; } v; v.f = f;
    unsigned int r = v.u + 0x7FFF + ((v.u >> 16) & 1);   // RNE
    return (unsigned short)(r >> 16);
}

// ---------------- degree + count ----------------
__global__ void degcnt_kernel(const int* __restrict__ dst, const float* __restrict__ w,
                              float* __restrict__ deg, int* __restrict__ cnt, int E) {
    int e = blockIdx.x * blockDim.x + threadIdx.x;
    if (e < E) {
        int d = dst[e];
        atomicAdd(&deg[d], w[e]);
        atomicAdd(&cnt[d], 1);
    }
}

// ---------------- CSR scan ----------------
__global__ void scan_kernel(const int* __restrict__ cnt, int* __restrict__ row_start, int N) {
    __shared__ int partial[256];
    int t = threadIdx.x;
    int chunk = (N + 255) / 256;
    int begin = t * chunk;
    int end = begin + chunk; if (end > N) end = N;
    int s = 0;
    for (int i = begin; i < end; i++) s += cnt[i];
    partial[t] = s;
    __syncthreads();
    for (int off = 1; off < 256; off <<= 1) {
        int v = (t >= off) ? partial[t - off] : 0;
        __syncthreads();
        partial[t] += v;
        __syncthreads();
    }
    int base = (t == 0) ? 0 : partial[t - 1];
    int run = base;
    for (int i = begin; i < end; i++) { row_start[i] = run; run += cnt[i]; }
    if (t == 255) row_start[N] = partial[255];
}

// fill dst-sorted edge arrays with INLINE norm: wnrm = dinv[src]*w*dinv[dst]
__global__ void fill_kernel(const int* __restrict__ dst, const int* __restrict__ src,
                            const float* __restrict__ w, const float* __restrict__ deg,
                            const int* __restrict__ row_start, int* __restrict__ cursor,
                            int* __restrict__ src_s, float* __restrict__ wnrm_s, int E) {
    int e = blockIdx.x * blockDim.x + threadIdx.x;
    if (e < E) {
        int d = dst[e], s = src[e];
        float dd = deg[d], ds = deg[s];
        float nv = (ds > 0.f ? rsqrtf(ds) : 0.f) * w[e] * (dd > 0.f ? rsqrtf(dd) : 0.f);
        int pos = row_start[d] + atomicAdd(&cursor[d], 1);
        src_s[pos] = s;
        wnrm_s[pos] = nv;
    }
}

// ---------------- aggNF[d, 0:320] (bf16, zero-padded) = sum w*nf[src,:] --------
// one wave per node
__global__ __launch_bounds__(64) void aggnf_kernel(const float* __restrict__ nf,
        const int* __restrict__ row_start, const int* __restrict__ src_s,
        const float* __restrict__ wnrm_s, unsigned short* __restrict__ out) {
    int d = blockIdx.x;
    int lane = threadIdx.x;
    int s0 = row_start[d], s1 = row_start[d + 1];
    unsigned short* orow = out + (long)d * KPAD1;
    for (int f4 = lane; f4 < 75; f4 += 64) {
        float4 acc = make_float4(0.f, 0.f, 0.f, 0.f);
        for (int idx = s0; idx < s1; idx++) {
            float w = wnrm_s[idx];
            float4 hv = ((const float4*)(nf + (long)src_s[idx] * FTEXT))[f4];
            acc.x += hv.x * w; acc.y += hv.y * w; acc.z += hv.z * w; acc.w += hv.w * w;
        }
        ushort4 o;
        o.x = f2bf(acc.x); o.y = f2bf(acc.y); o.z = f2bf(acc.z); o.w = f2bf(acc.w);
        ((ushort4*)orow)[f4] = o;
    }
    if (lane < 5) {  // zero pad k=300..319
        ushort4 z; z.x = z.y = z.z = z.w = 0;
        ((ushort4*)(orow + 300))[lane] = z;
    }
}

// ---------------- W1bt[n][k] (bf16, k zero-padded to 320) = W1[k][n] ----------
__global__ void cvtW1_kernel(const float* __restrict__ W1, unsigned short* __restrict__ W1bt) {
    int idx = blockIdx.x * 256 + threadIdx.x;
    if (idx >= HIDDIM * KPAD1) return;
    int n = idx / KPAD1, k = idx % KPAD1;
    float v = (k < FTEXT) ? W1[(long)k * HIDDIM + n] : 0.f;
    W1bt[idx] = f2bf(v);
}

// ---------------- two-range fp32 -> bf16 ----------------
__global__ void cvt2_kernel(const float* __restrict__ in1, unsigned short* __restrict__ out1,
                            int n1, const float* __restrict__ in2,
                            unsigned short* __restrict__ out2, int n2) {
    int i = blockIdx.x * 256 + threadIdx.x;
    if (i < n1) out1[i] = f2bf(in1[i]);
    else if (i < n1 + n2) out2[i - n1] = f2bf(in2[i - n1]);
}

__global__ void cvt_kernel(const float* __restrict__ in, unsigned short* __restrict__ out, int n) {
    int i = blockIdx.x * 256 + threadIdx.x;
    if (i < n) out[i] = f2bf(in[i]);
}

// ---------------- bf16 MFMA GEMM: C[M x N] = A[M x K] @ B^T, B is [N x K] ------
// Tile 128x64, BK=32, 256 threads = 4 waves, wave w owns rows [32w,32w+32).
// A/B^T frag: [lane&15][quad*8+j]; C/D: col=lane&15, row=quad*4+reg.
template<int EPI, int OUT_BF16, int ATOMIC>
__global__ __launch_bounds__(256) void mfma_gemm(
        const unsigned short* __restrict__ A, const unsigned short* __restrict__ B,
        const float* __restrict__ bias, void* __restrict__ Cv,
        int M, int N, int K, int ldc) {
    __shared__ unsigned short As[128][40];
    __shared__ unsigned short Bs[64][40];
    int t = threadIdx.x;
    int m0 = blockIdx.y * 128;
    int n0 = blockIdx.x * 64;
    int klen = K / gridDim.z;
    int kbeg = blockIdx.z * klen;
    int wave = t >> 6, lane = t & 63;
    int lm = lane & 15, lq = lane >> 4;
    floatx4 acc[2][4] = {};
    for (int k0 = kbeg; k0 < kbeg + klen; k0 += 32) {
        #pragma unroll
        for (int p = 0; p < 2; p++) {
            int idx = p * 256 + t;
            int r = idx >> 2, c8 = (idx & 3) * 8;
            uint4 v = make_uint4(0, 0, 0, 0);
            int gm = m0 + r;
            if (gm < M) v = *(const uint4*)(A + (long)gm * K + k0 + c8);
            *(uint4*)&As[r][c8] = v;
        }
        {
            int r = t >> 2, c8 = (t & 3) * 8;
            uint4 v = *(const uint4*)(B + (long)(n0 + r) * K + k0 + c8);
            *(uint4*)&Bs[r][c8] = v;
        }
        __syncthreads();
        short8 a[2], b[4];
        #pragma unroll
        for (int rt = 0; rt < 2; rt++)
            a[rt] = *(const short8*)&As[wave * 32 + rt * 16 + lm][lq * 8];
        #pragma unroll
        for (int ct = 0; ct < 4; ct++)
            b[ct] = *(const short8*)&Bs[ct * 16 + lm][lq * 8];
        #pragma unroll
        for (int rt = 0; rt < 2; rt++)
            #pragma unroll
            for (int ct = 0; ct < 4; ct++)
                acc[rt][ct] = __builtin_amdgcn_mfma_f32_16x16x32_bf16(
                    a[rt], b[ct], acc[rt][ct], 0, 0, 0);
        __syncthreads();
    }
    #pragma unroll
    for (int rt = 0; rt < 2; rt++) {
        #pragma unroll
        for (int r = 0; r < 4; r++) {
            int gm = m0 + wave * 32 + rt * 16 + lq * 4 + r;
            if (gm >= M) continue;
            #pragma unroll
            for (int ct = 0; ct < 4; ct++) {
                int gn = n0 + ct * 16 + lm;
                float v = acc[rt][ct][r];
                if (EPI) { v += bias[gn]; v = v >= 0.f ? v : 0.2f * v; }
                if (OUT_BF16)      ((unsigned short*)Cv)[(long)gm * ldc + gn] = f2bf(v);
                else if (ATOMIC)   atomicAdd((float*)Cv + (long)gm * ldc + gn, v);
                else               ((float*)Cv)[(long)gm * ldc + gn] = v;
            }
        }
    }
}

// ---------------- c[b] = img[b,:] . b2 ----------------
__global__ __launch_bounds__(64) void cvec_kernel(const float* __restrict__ img,
        const float* __restrict__ b2, float* __restrict__ c, int K) {
    int b = blockIdx.x;
    int l = threadIdx.x;
    float v = 0.f;
    for (int f = l; f < K; f += 64) v += img[(long)b * K + f] * b2[f];
    for (int off = 32; off > 0; off >>= 1) v += __shfl_down(v, off);
    if (l == 0) c[b] = v;
}

// ---------------- out[b,d] = sum_{e:dst=d} w*Y[src,b] + c[b] ------------------
// one WAVE per dst node (4/block); lane = b; pipelined edge loop; LDS transpose.
__global__ __launch_bounds__(256) void outagg_kernel(const float* __restrict__ Y,
        const int* __restrict__ row_start, const int* __restrict__ src_s,
        const float* __restrict__ wnrm_s, const float* __restrict__ c,
        float* __restrict__ out, int N) {
    __shared__ float tile[4][68];
    int d0 = blockIdx.x * 4;
    int t = threadIdx.x;
    int wave = t >> 6, lane = t & 63;
    int d = d0 + wave;
    int s0 = row_start[d], s1 = row_start[d + 1];
    float acc = 0.f;
    int scur = 0; float wcur = 0.f;
    if (s0 < s1) { scur = src_s[s0]; wcur = wnrm_s[s0]; }
    for (int idx = s0; idx < s1; idx++) {
        int snext = 0; float wnext = 0.f;
        if (idx + 1 < s1) { snext = src_s[idx + 1]; wnext = wnrm_s[idx + 1]; }
        acc += wcur * Y[(long)scur * 64 + lane];
        scur = snext; wcur = wnext;
    }
    tile[wave][lane] = acc + c[lane];
    __syncthreads();
    int b = t >> 2, j = t & 3;
    out[(long)b * N + d0 + j] = tile[j][b];
}

extern "C" void kernel_launch(void* const* d_in, const int* in_sizes, int n_in,
                              void* d_out, int out_size, void* d_ws, size_t ws_size,
                              hipStream_t stream) {
    const float* img_feat      = (const float*)d_in[0];
    const float* node_features = (const float*)d_in[1];
    const int*   edge_src      = (const int*)d_in[2];
    const int*   edge_dst      = (const int*)d_in[3];
    const float* edge_weight   = (const float*)d_in[4];
    const float* W1            = (const float*)d_in[5];
    const float* b1            = (const float*)d_in[6];
    const float* W2            = (const float*)d_in[7];
    const float* b2            = (const float*)d_in[8];
    float* out = (float*)d_out;

    const int N = NNODES, E = NEDGES;

    char* ws = (char*)d_ws;
    size_t off = 0;
    auto alloc = [&](size_t bytes) -> void* {
        void* p = ws + off;
        off = (off + bytes + 255) & ~(size_t)255;
        return p;
    };
    // ---- zero-initialized region (single memset) ----
    float*          deg       = (float*)alloc((size_t)N * 4);
    int*            cnt       = (int*)alloc((size_t)N * 4);
    int*            cursor    = (int*)alloc((size_t)N * 4);
    float*          Ztf       = (float*)alloc((size_t)BQ * HIDDIM * 4);
    float*          Y         = (float*)alloc((size_t)N * BQ * 4);               // 5.1 MB
    size_t zero_bytes = off;
    // ---- rest ----
    int*            row_start = (int*)alloc((size_t)(N + 1) * 4);
    int*            src_s     = (int*)alloc((size_t)E * 4);
    float*          wnrm_s    = (float*)alloc((size_t)E * 4);
    unsigned short* aggNF     = (unsigned short*)alloc((size_t)N * KPAD1 * 2);   // 12.8 MB
    unsigned short* W1bt      = (unsigned short*)alloc((size_t)HIDDIM * KPAD1 * 2);
    unsigned short* x         = (unsigned short*)alloc((size_t)N * HIDDIM * 2);  // 41 MB
    unsigned short* W2b       = (unsigned short*)alloc((size_t)HIDDIM * OUTDIM * 2); // 3.4 MB
    unsigned short* imgb      = (unsigned short*)alloc((size_t)BQ * OUTDIM * 2);
    unsigned short* Zt        = (unsigned short*)alloc((size_t)BQ * HIDDIM * 2);
    float*          cvec      = (float*)alloc((size_t)BQ * 4);

    hipMemsetAsync(ws, 0, zero_bytes, stream);

    int eb = (E + 255) / 256;
    degcnt_kernel<<<eb, 256, 0, stream>>>(edge_dst, edge_weight, deg, cnt, E);
    scan_kernel<<<1, 256, 0, stream>>>(cnt, row_start, N);
    fill_kernel<<<eb, 256, 0, stream>>>(edge_dst, edge_src, edge_weight, deg, row_start,
                                        cursor, src_s, wnrm_s, E);

    // weight conversions
    cvtW1_kernel<<<(HIDDIM * KPAD1 + 255) / 256, 256, 0, stream>>>(W1, W1bt);
    cvt2_kernel<<<(HIDDIM * OUTDIM + BQ * OUTDIM + 255) / 256, 256, 0, stream>>>(
        W2, W2b, HIDDIM * OUTDIM, img_feat, imgb, BQ * OUTDIM);

    // Ztf = img @ W2^T  [64 x 1024]  (MFMA, split-K=13, fp32 atomic); Zt = bf16(Ztf)
    mfma_gemm<0, 0, 1><<<dim3(HIDDIM / 64, 1, 13), 256, 0, stream>>>(
        imgb, W2b, nullptr, Ztf, BQ, HIDDIM, OUTDIM, HIDDIM);
    cvt_kernel<<<(BQ * HIDDIM + 255) / 256, 256, 0, stream>>>(Ztf, Zt, BQ * HIDDIM);

    // aggNF = bf16(A @ node_features), k-padded
    aggnf_kernel<<<N, 64, 0, stream>>>(node_features, row_start, src_s, wnrm_s, aggNF);

    // x = bf16(leaky(aggNF @ W1 + b1))   [N x 1024]   (MFMA)
    mfma_gemm<1, 1, 0><<<dim3(HIDDIM / 64, (N + 127) / 128, 1), 256, 0, stream>>>(
        aggNF, W1bt, b1, x, N, HIDDIM, KPAD1, HIDDIM);

    // Y += x @ Zt^T   [N x 64]   (MFMA, split-K=4, fp32 atomic accumulate)
    mfma_gemm<0, 0, 1><<<dim3(1, (N + 127) / 128, 4), 256, 0, stream>>>(
        x, Zt, nullptr, Y, N, BQ, HIDDIM, BQ);

    cvec_kernel<<<BQ, 64, 0, stream>>>(img_feat, b2, cvec, OUTDIM);
    outagg_kernel<<<N / 4, 256, 0, stream>>>(Y, row_start, src_s, wnrm_s, cvec, out, N);
}

// Round 7
// 288.475 us; speedup vs baseline: 2.9424x; 1.0071x over previous
//
#include <hip/hip_runtime.h>
#include <hip/hip_bf16.h>

#define NNODES 20000
#define NEDGES 160000
#define BQ     64
#define FTEXT  300
#define KPAD1  320          // FTEXT padded to multiple of 32
#define HIDDIM 1024
#define OUTDIM 1664

typedef __attribute__((ext_vector_type(8))) short short8;
typedef __attribute__((ext_vector_type(4))) float floatx4;

__device__ inline unsigned short f2bf(float f) {
    union { float f; unsigned int u; } v; v.f = f;
    unsigned int r = v.u + 0x7FFF + ((v.u >> 16) & 1);   // RNE
    return (unsigned short)(r >> 16);
}
__device__ inline float bf2f(unsigned short h) {
    union { unsigned int u; float f; } v; v.u = ((unsigned int)h) << 16;
    return v.f;
}

// ---------------- degree + count ----------------
__global__ void degcnt_kernel(const int* __restrict__ dst, const float* __restrict__ w,
                              float* __restrict__ deg, int* __restrict__ cnt, int E) {
    int e = blockIdx.x * blockDim.x + threadIdx.x;
    if (e < E) {
        int d = dst[e];
        atomicAdd(&deg[d], w[e]);
        atomicAdd(&cnt[d], 1);
    }
}

// ---------------- CSR scan ----------------
__global__ void scan_kernel(const int* __restrict__ cnt, int* __restrict__ row_start, int N) {
    __shared__ int partial[256];
    int t = threadIdx.x;
    int chunk = (N + 255) / 256;
    int begin = t * chunk;
    int end = begin + chunk; if (end > N) end = N;
    int s = 0;
    for (int i = begin; i < end; i++) s += cnt[i];
    partial[t] = s;
    __syncthreads();
    for (int off = 1; off < 256; off <<= 1) {
        int v = (t >= off) ? partial[t - off] : 0;
        __syncthreads();
        partial[t] += v;
        __syncthreads();
    }
    int base = (t == 0) ? 0 : partial[t - 1];
    int run = base;
    for (int i = begin; i < end; i++) { row_start[i] = run; run += cnt[i]; }
    if (t == 255) row_start[N] = partial[255];
}

// fill dst-sorted edge arrays with INLINE norm: wnrm = dinv[src]*w*dinv[dst]
__global__ void fill_kernel(const int* __restrict__ dst, const int* __restrict__ src,
                            const float* __restrict__ w, const float* __restrict__ deg,
                            const int* __restrict__ row_start, int* __restrict__ cursor,
                            int* __restrict__ src_s, float* __restrict__ wnrm_s, int E) {
    int e = blockIdx.x * blockDim.x + threadIdx.x;
    if (e < E) {
        int d = dst[e], s = src[e];
        float dd = deg[d], ds = deg[s];
        float nv = (ds > 0.f ? rsqrtf(ds) : 0.f) * w[e] * (dd > 0.f ? rsqrtf(dd) : 0.f);
        int pos = row_start[d] + atomicAdd(&cursor[d], 1);
        src_s[pos] = s;
        wnrm_s[pos] = nv;
    }
}

// ---------------- aggNF[d, 0:320] (bf16, zero-padded) = sum w*nfb[src,:] -------
// one wave per node; nfb is bf16 [N x 300]; ushort4 gathers (8B) halve L3 traffic
__global__ __launch_bounds__(64) void aggnf_kernel(const unsigned short* __restrict__ nfb,
        const int* __restrict__ row_start, const int* __restrict__ src_s,
        const float* __restrict__ wnrm_s, unsigned short* __restrict__ out) {
    int d = blockIdx.x;
    int lane = threadIdx.x;
    int s0 = row_start[d], s1 = row_start[d + 1];
    unsigned short* orow = out + (long)d * KPAD1;
    for (int f4 = lane; f4 < 75; f4 += 64) {
        float4 acc = make_float4(0.f, 0.f, 0.f, 0.f);
        for (int idx = s0; idx < s1; idx++) {
            float w = wnrm_s[idx];
            ushort4 hv = ((const ushort4*)(nfb + (long)src_s[idx] * FTEXT))[f4];
            acc.x += bf2f(hv.x) * w; acc.y += bf2f(hv.y) * w;
            acc.z += bf2f(hv.z) * w; acc.w += bf2f(hv.w) * w;
        }
        ushort4 o;
        o.x = f2bf(acc.x); o.y = f2bf(acc.y); o.z = f2bf(acc.z); o.w = f2bf(acc.w);
        ((ushort4*)orow)[f4] = o;
    }
    if (lane < 5) {  // zero pad k=300..319
        ushort4 z; z.x = z.y = z.z = z.w = 0;
        ((ushort4*)(orow + 300))[lane] = z;
    }
}

// ---------------- W1bt[n][k] (bf16, k zero-padded to 320) = W1[k][n] ----------
__global__ void cvtW1_kernel(const float* __restrict__ W1, unsigned short* __restrict__ W1bt) {
    int idx = blockIdx.x * 256 + threadIdx.x;
    if (idx >= HIDDIM * KPAD1) return;
    int n = idx / KPAD1, k = idx % KPAD1;
    float v = (k < FTEXT) ? W1[(long)k * HIDDIM + n] : 0.f;
    W1bt[idx] = f2bf(v);
}

// ---------------- three-range fp32 -> bf16, float4-vectorized -----------------
#define N1F4 (HIDDIM * OUTDIM / 4)          // W2
#define N2F4 (BQ * OUTDIM / 4)              // img
#define N3F4 (NNODES * FTEXT / 4)           // nf
__global__ void cvt3_kernel(const float* __restrict__ in1, unsigned short* __restrict__ out1,
                            const float* __restrict__ in2, unsigned short* __restrict__ out2,
                            const float* __restrict__ in3, unsigned short* __restrict__ out3) {
    int i = blockIdx.x * 256 + threadIdx.x;
    const float* in; unsigned short* outp; int j;
    if (i < N1F4)                { in = in1; outp = out1; j = i; }
    else if (i < N1F4 + N2F4)    { in = in2; outp = out2; j = i - N1F4; }
    else if (i < N1F4 + N2F4 + N3F4) { in = in3; outp = out3; j = i - N1F4 - N2F4; }
    else return;
    float4 v = ((const float4*)in)[j];
    ushort4 o;
    o.x = f2bf(v.x); o.y = f2bf(v.y); o.z = f2bf(v.z); o.w = f2bf(v.w);
    ((ushort4*)outp)[j] = o;
}

__global__ void cvt_kernel(const float* __restrict__ in, unsigned short* __restrict__ out, int n) {
    int i = blockIdx.x * 256 + threadIdx.x;
    if (i < n) out[i] = f2bf(in[i]);
}

// ---------------- bf16 MFMA GEMM: C[M x N] = A[M x K] @ B^T, B is [N x K] ------
// Tile 128 x NT, BK=32, 256 threads = 4 waves, wave w owns rows [32w,32w+32).
// A/B^T frag: [lane&15][quad*8+j]; C/D: col=lane&15, row=quad*4+reg.
template<int EPI, int OUT_BF16, int ATOMIC, int NT>
__global__ __launch_bounds__(256) void mfma_gemm(
        const unsigned short* __restrict__ A, const unsigned short* __restrict__ B,
        const float* __restrict__ bias, void* __restrict__ Cv,
        int M, int N, int K, int ldc) {
    constexpr int CT = NT / 16;
    __shared__ unsigned short As[128][40];
    __shared__ unsigned short Bs[NT][40];
    int t = threadIdx.x;
    int m0 = blockIdx.y * 128;
    int n0 = blockIdx.x * NT;
    int klen = K / gridDim.z;
    int kbeg = blockIdx.z * klen;
    int wave = t >> 6, lane = t & 63;
    int lm = lane & 15, lq = lane >> 4;
    floatx4 acc[2][CT] = {};
    for (int k0 = kbeg; k0 < kbeg + klen; k0 += 32) {
        #pragma unroll
        for (int p = 0; p < 2; p++) {
            int idx = p * 256 + t;
            int r = idx >> 2, c8 = (idx & 3) * 8;
            uint4 v = make_uint4(0, 0, 0, 0);
            int gm = m0 + r;
            if (gm < M) v = *(const uint4*)(A + (long)gm * K + k0 + c8);
            *(uint4*)&As[r][c8] = v;
        }
        #pragma unroll
        for (int p = 0; p < NT / 64; p++) {
            int idx = p * 256 + t;
            int r = idx >> 2, c8 = (idx & 3) * 8;
            uint4 v = *(const uint4*)(B + (long)(n0 + r) * K + k0 + c8);
            *(uint4*)&Bs[r][c8] = v;
        }
        __syncthreads();
        short8 a[2], b[CT];
        #pragma unroll
        for (int rt = 0; rt < 2; rt++)
            a[rt] = *(const short8*)&As[wave * 32 + rt * 16 + lm][lq * 8];
        #pragma unroll
        for (int ct = 0; ct < CT; ct++)
            b[ct] = *(const short8*)&Bs[ct * 16 + lm][lq * 8];
        #pragma unroll
        for (int rt = 0; rt < 2; rt++)
            #pragma unroll
            for (int ct = 0; ct < CT; ct++)
                acc[rt][ct] = __builtin_amdgcn_mfma_f32_16x16x32_bf16(
                    a[rt], b[ct], acc[rt][ct], 0, 0, 0);
        __syncthreads();
    }
    #pragma unroll
    for (int rt = 0; rt < 2; rt++) {
        #pragma unroll
        for (int r = 0; r < 4; r++) {
            int gm = m0 + wave * 32 + rt * 16 + lq * 4 + r;
            if (gm >= M) continue;
            #pragma unroll
            for (int ct = 0; ct < CT; ct++) {
                int gn = n0 + ct * 16 + lm;
                float v = acc[rt][ct][r];
                if (EPI) { v += bias[gn]; v = v >= 0.f ? v : 0.2f * v; }
                if (OUT_BF16)      ((unsigned short*)Cv)[(long)gm * ldc + gn] = f2bf(v);
                else if (ATOMIC)   atomicAdd((float*)Cv + (long)gm * ldc + gn, v);
                else               ((float*)Cv)[(long)gm * ldc + gn] = v;
            }
        }
    }
}

// ---------------- c[b] = img[b,:] . b2 ----------------
__global__ __launch_bounds__(64) void cvec_kernel(const float* __restrict__ img,
        const float* __restrict__ b2, float* __restrict__ c, int K) {
    int b = blockIdx.x;
    int l = threadIdx.x;
    float v = 0.f;
    for (int f = l; f < K; f += 64) v += img[(long)b * K + f] * b2[f];
    for (int off = 32; off > 0; off >>= 1) v += __shfl_down(v, off);
    if (l == 0) c[b] = v;
}

// ---------------- out[b,d] = sum_{e:dst=d} w*Y[src,b] + c[b] ------------------
// one WAVE per dst node (4/block); lane = b; pipelined edge loop; LDS transpose.
__global__ __launch_bounds__(256) void outagg_kernel(const float* __restrict__ Y,
        const int* __restrict__ row_start, const int* __restrict__ src_s,
        const float* __restrict__ wnrm_s, const float* __restrict__ c,
        float* __restrict__ out, int N) {
    __shared__ float tile[4][68];
    int d0 = blockIdx.x * 4;
    int t = threadIdx.x;
    int wave = t >> 6, lane = t & 63;
    int d = d0 + wave;
    int s0 = row_start[d], s1 = row_start[d + 1];
    float acc = 0.f;
    int scur = 0; float wcur = 0.f;
    if (s0 < s1) { scur = src_s[s0]; wcur = wnrm_s[s0]; }
    for (int idx = s0; idx < s1; idx++) {
        int snext = 0; float wnext = 0.f;
        if (idx + 1 < s1) { snext = src_s[idx + 1]; wnext = wnrm_s[idx + 1]; }
        acc += wcur * Y[(long)scur * 64 + lane];
        scur = snext; wcur = wnext;
    }
    tile[wave][lane] = acc + c[lane];
    __syncthreads();
    int b = t >> 2, j = t & 3;
    out[(long)b * N + d0 + j] = tile[j][b];
}

extern "C" void kernel_launch(void* const* d_in, const int* in_sizes, int n_in,
                              void* d_out, int out_size, void* d_ws, size_t ws_size,
                              hipStream_t stream) {
    const float* img_feat      = (const float*)d_in[0];
    const float* node_features = (const float*)d_in[1];
    const int*   edge_src      = (const int*)d_in[2];
    const int*   edge_dst      = (const int*)d_in[3];
    const float* edge_weight   = (const float*)d_in[4];
    const float* W1            = (const float*)d_in[5];
    const float* b1            = (const float*)d_in[6];
    const float* W2            = (const float*)d_in[7];
    const float* b2            = (const float*)d_in[8];
    float* out = (float*)d_out;

    const int N = NNODES, E = NEDGES;

    char* ws = (char*)d_ws;
    size_t off = 0;
    auto alloc = [&](size_t bytes) -> void* {
        void* p = ws + off;
        off = (off + bytes + 255) & ~(size_t)255;
        return p;
    };
    // ---- zero-initialized region (single memset) ----
    float*          deg       = (float*)alloc((size_t)N * 4);
    int*            cnt       = (int*)alloc((size_t)N * 4);
    int*            cursor    = (int*)alloc((size_t)N * 4);
    float*          Ztf       = (float*)alloc((size_t)BQ * HIDDIM * 4);
    float*          Y         = (float*)alloc((size_t)N * BQ * 4);               // 5.1 MB
    size_t zero_bytes = off;
    // ---- rest ----
    int*            row_start = (int*)alloc((size_t)(N + 1) * 4);
    int*            src_s     = (int*)alloc((size_t)E * 4);
    float*          wnrm_s    = (float*)alloc((size_t)E * 4);
    unsigned short* aggNF     = (unsigned short*)alloc((size_t)N * KPAD1 * 2);   // 12.8 MB
    unsigned short* W1bt      = (unsigned short*)alloc((size_t)HIDDIM * KPAD1 * 2);
    unsigned short* x         = (unsigned short*)alloc((size_t)N * HIDDIM * 2);  // 41 MB
    unsigned short* W2b       = (unsigned short*)alloc((size_t)HIDDIM * OUTDIM * 2); // 3.4 MB
    unsigned short* imgb      = (unsigned short*)alloc((size_t)BQ * OUTDIM * 2);
    unsigned short* nfb       = (unsigned short*)alloc((size_t)N * FTEXT * 2);   // 12 MB
    unsigned short* Zt        = (unsigned short*)alloc((size_t)BQ * HIDDIM * 2);
    float*          cvec      = (float*)alloc((size_t)BQ * 4);

    hipMemsetAsync(ws, 0, zero_bytes, stream);

    int eb = (E + 255) / 256;
    degcnt_kernel<<<eb, 256, 0, stream>>>(edge_dst, edge_weight, deg, cnt, E);
    scan_kernel<<<1, 256, 0, stream>>>(cnt, row_start, N);
    fill_kernel<<<eb, 256, 0, stream>>>(edge_dst, edge_src, edge_weight, deg, row_start,
                                        cursor, src_s, wnrm_s, E);

    // weight / input conversions (W2, img, nf in one pass; W1 transpose separate)
    cvtW1_kernel<<<(HIDDIM * KPAD1 + 255) / 256, 256, 0, stream>>>(W1, W1bt);
    cvt3_kernel<<<(N1F4 + N2F4 + N3F4 + 255) / 256, 256, 0, stream>>>(
        W2, W2b, img_feat, imgb, node_features, nfb);

    // Ztf = img @ W2^T  [64 x 1024]  (MFMA, split-K=13, fp32 atomic); Zt = bf16(Ztf)
    mfma_gemm<0, 0, 1, 64><<<dim3(HIDDIM / 64, 1, 13), 256, 0, stream>>>(
        imgb, W2b, nullptr, Ztf, BQ, HIDDIM, OUTDIM, HIDDIM);
    cvt_kernel<<<(BQ * HIDDIM + 255) / 256, 256, 0, stream>>>(Ztf, Zt, BQ * HIDDIM);

    // aggNF = bf16(A @ nfb), k-padded
    aggnf_kernel<<<N, 64, 0, stream>>>(nfb, row_start, src_s, wnrm_s, aggNF);

    // x = bf16(leaky(aggNF @ W1 + b1))   [N x 1024]   (MFMA, 128x128 tile)
    mfma_gemm<1, 1, 0, 128><<<dim3(HIDDIM / 128, (N + 127) / 128, 1), 256, 0, stream>>>(
        aggNF, W1bt, b1, x, N, HIDDIM, KPAD1, HIDDIM);

    // Y += x @ Zt^T   [N x 64]   (MFMA, split-K=4, fp32 atomic accumulate)
    mfma_gemm<0, 0, 1, 64><<<dim3(1, (N + 127) / 128, 4), 256, 0, stream>>>(
        x, Zt, nullptr, Y, N, BQ, HIDDIM, BQ);

    cvec_kernel<<<BQ, 64, 0, stream>>>(img_feat, b2, cvec, OUTDIM);
    outagg_kernel<<<N / 4, 256, 0, stream>>>(Y, row_start, src_s, wnrm_s, cvec, out, N);
}

// Round 8
// 270.170 us; speedup vs baseline: 3.1417x; 1.0678x over previous
//
#include <hip/hip_runtime.h>
#include <hip/hip_bf16.h>

#define NNODES 20000
#define NEDGES 160000
#define BQ     64
#define FTEXT  300
#define KPAD1  320          // FTEXT padded to multiple of 32
#define HIDDIM 1024
#define OUTDIM 1664

typedef __attribute__((ext_vector_type(8))) short short8;
typedef __attribute__((ext_vector_type(4))) float floatx4;

__device__ inline unsigned short f2bf(float f) {
    union { float f; unsigned int u; } v; v.f = f;
    unsigned int r = v.u + 0x7FFF + ((v.u >> 16) & 1);   // RNE
    return (unsigned short)(r >> 16);
}
__device__ inline float bf2f(unsigned short h) {
    union { unsigned int u; float f; } v; v.u = ((unsigned int)h) << 16;
    return v.f;
}

// ---------------- degree + count ----------------
__global__ void degcnt_kernel(const int* __restrict__ dst, const float* __restrict__ w,
                              float* __restrict__ deg, int* __restrict__ cnt, int E) {
    int e = blockIdx.x * blockDim.x + threadIdx.x;
    if (e < E) {
        int d = dst[e];
        atomicAdd(&deg[d], w[e]);
        atomicAdd(&cnt[d], 1);
    }
}

// ---------------- CSR scan: 1024 threads, int4-vectorized, LDS prefix --------
__global__ __launch_bounds__(1024) void scan_kernel(const int* __restrict__ cnt,
                                                    int* __restrict__ row_start, int N) {
    __shared__ int partial[1024];
    const int CH = 20;                       // 1024*20 >= N; N=20000 -> 1000 full threads
    int t = threadIdx.x;
    int begin = t * CH;
    int nloc = N - begin; if (nloc > CH) nloc = CH; if (nloc < 0) nloc = 0;
    int vals[CH];
    int s = 0;
    if (nloc == CH) {
        #pragma unroll
        for (int i = 0; i < CH / 4; i++) {
            int4 v = ((const int4*)(cnt + begin))[i];
            vals[i*4+0] = v.x; vals[i*4+1] = v.y; vals[i*4+2] = v.z; vals[i*4+3] = v.w;
            s += v.x + v.y + v.z + v.w;
        }
    } else {
        for (int i = 0; i < nloc; i++) { vals[i] = cnt[begin + i]; s += vals[i]; }
    }
    partial[t] = s;
    __syncthreads();
    for (int off = 1; off < 1024; off <<= 1) {
        int v = (t >= off) ? partial[t - off] : 0;
        __syncthreads();
        partial[t] += v;
        __syncthreads();
    }
    int run = (t == 0) ? 0 : partial[t - 1];
    for (int i = 0; i < nloc; i++) { row_start[begin + i] = run; run += vals[i]; }
    if (t == 1023) row_start[N] = partial[1023];
}

// fill dst-sorted edge arrays with INLINE norm: wnrm = dinv[src]*w*dinv[dst]
__global__ void fill_kernel(const int* __restrict__ dst, const int* __restrict__ src,
                            const float* __restrict__ w, const float* __restrict__ deg,
                            const int* __restrict__ row_start, int* __restrict__ cursor,
                            int* __restrict__ src_s, float* __restrict__ wnrm_s, int E) {
    int e = blockIdx.x * blockDim.x + threadIdx.x;
    if (e < E) {
        int d = dst[e], s = src[e];
        float dd = deg[d], ds = deg[s];
        float nv = (ds > 0.f ? rsqrtf(ds) : 0.f) * w[e] * (dd > 0.f ? rsqrtf(dd) : 0.f);
        int pos = row_start[d] + atomicAdd(&cursor[d], 1);
        src_s[pos] = s;
        wnrm_s[pos] = nv;
    }
}

// ---------------- aggNF[d, 0:320] (bf16, zero-padded) = sum w*nfb[src,:] -------
// 4 waves/block, one wave per node -> full occupancy (vs 64-thread blocks)
__global__ __launch_bounds__(256) void aggnf_kernel(const unsigned short* __restrict__ nfb,
        const int* __restrict__ row_start, const int* __restrict__ src_s,
        const float* __restrict__ wnrm_s, unsigned short* __restrict__ out) {
    int wave = threadIdx.x >> 6, lane = threadIdx.x & 63;
    int d = blockIdx.x * 4 + wave;
    int s0 = row_start[d], s1 = row_start[d + 1];
    unsigned short* orow = out + (long)d * KPAD1;
    for (int f4 = lane; f4 < 75; f4 += 64) {
        float4 acc = make_float4(0.f, 0.f, 0.f, 0.f);
        for (int idx = s0; idx < s1; idx++) {
            float w = wnrm_s[idx];
            ushort4 hv = ((const ushort4*)(nfb + (long)src_s[idx] * FTEXT))[f4];
            acc.x += bf2f(hv.x) * w; acc.y += bf2f(hv.y) * w;
            acc.z += bf2f(hv.z) * w; acc.w += bf2f(hv.w) * w;
        }
        ushort4 o;
        o.x = f2bf(acc.x); o.y = f2bf(acc.y); o.z = f2bf(acc.z); o.w = f2bf(acc.w);
        ((ushort4*)orow)[f4] = o;
    }
    if (lane < 5) {  // zero pad k=300..319
        ushort4 z; z.x = z.y = z.z = z.w = 0;
        ((ushort4*)(orow + 300))[lane] = z;
    }
}

// ---------------- all weight/input conversions in ONE kernel ------------------
// range 0: W1 [300x1024] -> W1bt [1024][320] bf16 transposed+padded (element-wise)
// range 1: W2 (f4), range 2: img (f4), range 3: nf (f4)
#define W1N  (HIDDIM * KPAD1)
#define N1F4 (HIDDIM * OUTDIM / 4)
#define N2F4 (BQ * OUTDIM / 4)
#define N3F4 (NNODES * FTEXT / 4)
__global__ void cvt_all_kernel(const float* __restrict__ W1, unsigned short* __restrict__ W1bt,
                               const float* __restrict__ W2, unsigned short* __restrict__ W2b,
                               const float* __restrict__ img, unsigned short* __restrict__ imgb,
                               const float* __restrict__ nf, unsigned short* __restrict__ nfb) {
    int i = blockIdx.x * 256 + threadIdx.x;
    if (i < W1N) {
        int n = i / KPAD1, k = i % KPAD1;
        float v = (k < FTEXT) ? W1[(long)k * HIDDIM + n] : 0.f;
        W1bt[i] = f2bf(v);
        return;
    }
    i -= W1N;
    const float* in; unsigned short* outp; int j;
    if (i < N1F4)                    { in = W2;  outp = W2b;  j = i; }
    else if (i < N1F4 + N2F4)        { in = img; outp = imgb; j = i - N1F4; }
    else if (i < N1F4 + N2F4 + N3F4) { in = nf;  outp = nfb;  j = i - N1F4 - N2F4; }
    else return;
    float4 v = ((const float4*)in)[j];
    ushort4 o;
    o.x = f2bf(v.x); o.y = f2bf(v.y); o.z = f2bf(v.z); o.w = f2bf(v.w);
    ((ushort4*)outp)[j] = o;
}

// ---------------- Zt = bf16(Ztf)  +  cvec[b] = img[b,:].b2  (one kernel) ------
__global__ __launch_bounds__(256) void ztcvec_kernel(const float* __restrict__ Ztf,
        unsigned short* __restrict__ Zt, const float* __restrict__ img,
        const float* __restrict__ b2, float* __restrict__ cvec) {
    if (blockIdx.x < (BQ * HIDDIM) / 256) {
        int i = blockIdx.x * 256 + threadIdx.x;
        Zt[i] = f2bf(Ztf[i]);
    } else {
        int b = blockIdx.x - (BQ * HIDDIM) / 256;
        int l = threadIdx.x;
        float v = 0.f;
        for (int f = l; f < OUTDIM; f += 256) v += img[(long)b * OUTDIM + f] * b2[f];
        __shared__ float red[256];
        red[l] = v;
        __syncthreads();
        if (l < 64) {
            v = red[l] + red[l + 64] + red[l + 128] + red[l + 192];
            for (int off = 32; off > 0; off >>= 1) v += __shfl_down(v, off);
            if (l == 0) cvec[b] = v;
        }
    }
}

// ---------------- bf16 MFMA GEMM: C[M x N] = A[M x K] @ B^T, B is [N x K] ------
// Tile 128 x NT, BK=32, 256 threads = 4 waves, wave w owns rows [32w,32w+32).
// A/B^T frag: [lane&15][quad*8+j]; C/D: col=lane&15, row=quad*4+reg.
template<int EPI, int OUT_BF16, int ATOMIC, int NT>
__global__ __launch_bounds__(256) void mfma_gemm(
        const unsigned short* __restrict__ A, const unsigned short* __restrict__ B,
        const float* __restrict__ bias, void* __restrict__ Cv,
        int M, int N, int K, int ldc) {
    constexpr int CT = NT / 16;
    __shared__ unsigned short As[128][40];
    __shared__ unsigned short Bs[NT][40];
    int t = threadIdx.x;
    int m0 = blockIdx.y * 128;
    int n0 = blockIdx.x * NT;
    int klen = K / gridDim.z;
    int kbeg = blockIdx.z * klen;
    int wave = t >> 6, lane = t & 63;
    int lm = lane & 15, lq = lane >> 4;
    floatx4 acc[2][CT] = {};
    for (int k0 = kbeg; k0 < kbeg + klen; k0 += 32) {
        #pragma unroll
        for (int p = 0; p < 2; p++) {
            int idx = p * 256 + t;
            int r = idx >> 2, c8 = (idx & 3) * 8;
            uint4 v = make_uint4(0, 0, 0, 0);
            int gm = m0 + r;
            if (gm < M) v = *(const uint4*)(A + (long)gm * K + k0 + c8);
            *(uint4*)&As[r][c8] = v;
        }
        #pragma unroll
        for (int p = 0; p < NT / 64; p++) {
            int idx = p * 256 + t;
            int r = idx >> 2, c8 = (idx & 3) * 8;
            uint4 v = *(const uint4*)(B + (long)(n0 + r) * K + k0 + c8);
            *(uint4*)&Bs[r][c8] = v;
        }
        __syncthreads();
        short8 a[2], b[CT];
        #pragma unroll
        for (int rt = 0; rt < 2; rt++)
            a[rt] = *(const short8*)&As[wave * 32 + rt * 16 + lm][lq * 8];
        #pragma unroll
        for (int ct = 0; ct < CT; ct++)
            b[ct] = *(const short8*)&Bs[ct * 16 + lm][lq * 8];
        #pragma unroll
        for (int rt = 0; rt < 2; rt++)
            #pragma unroll
            for (int ct = 0; ct < CT; ct++)
                acc[rt][ct] = __builtin_amdgcn_mfma_f32_16x16x32_bf16(
                    a[rt], b[ct], acc[rt][ct], 0, 0, 0);
        __syncthreads();
    }
    #pragma unroll
    for (int rt = 0; rt < 2; rt++) {
        #pragma unroll
        for (int r = 0; r < 4; r++) {
            int gm = m0 + wave * 32 + rt * 16 + lq * 4 + r;
            if (gm >= M) continue;
            #pragma unroll
            for (int ct = 0; ct < CT; ct++) {
                int gn = n0 + ct * 16 + lm;
                float v = acc[rt][ct][r];
                if (EPI) { v += bias[gn]; v = v >= 0.f ? v : 0.2f * v; }
                if (OUT_BF16)      ((unsigned short*)Cv)[(long)gm * ldc + gn] = f2bf(v);
                else if (ATOMIC)   atomicAdd((float*)Cv + (long)gm * ldc + gn, v);
                else               ((float*)Cv)[(long)gm * ldc + gn] = v;
            }
        }
    }
}

// ---------------- out[b,d] = sum_{e:dst=d} w*Y[src,b] + c[b] ------------------
// one WAVE per dst node (4/block); lane = b; pipelined edge loop; LDS transpose.
__global__ __launch_bounds__(256) void outagg_kernel(const float* __restrict__ Y,
        const int* __restrict__ row_start, const int* __restrict__ src_s,
        const float* __restrict__ wnrm_s, const float* __restrict__ c,
        float* __restrict__ out, int N) {
    __shared__ float tile[4][68];
    int d0 = blockIdx.x * 4;
    int t = threadIdx.x;
    int wave = t >> 6, lane = t & 63;
    int d = d0 + wave;
    int s0 = row_start[d], s1 = row_start[d + 1];
    float acc = 0.f;
    int scur = 0; float wcur = 0.f;
    if (s0 < s1) { scur = src_s[s0]; wcur = wnrm_s[s0]; }
    for (int idx = s0; idx < s1; idx++) {
        int snext = 0; float wnext = 0.f;
        if (idx + 1 < s1) { snext = src_s[idx + 1]; wnext = wnrm_s[idx + 1]; }
        acc += wcur * Y[(long)scur * 64 + lane];
        scur = snext; wcur = wnext;
    }
    tile[wave][lane] = acc + c[lane];
    __syncthreads();
    int b = t >> 2, j = t & 3;
    out[(long)b * N + d0 + j] = tile[j][b];
}

extern "C" void kernel_launch(void* const* d_in, const int* in_sizes, int n_in,
                              void* d_out, int out_size, void* d_ws, size_t ws_size,
                              hipStream_t stream) {
    const float* img_feat      = (const float*)d_in[0];
    const float* node_features = (const float*)d_in[1];
    const int*   edge_src      = (const int*)d_in[2];
    const int*   edge_dst      = (const int*)d_in[3];
    const float* edge_weight   = (const float*)d_in[4];
    const float* W1            = (const float*)d_in[5];
    const float* b1            = (const float*)d_in[6];
    const float* W2            = (const float*)d_in[7];
    const float* b2            = (const float*)d_in[8];
    float* out = (float*)d_out;

    const int N = NNODES, E = NEDGES;

    char* ws = (char*)d_ws;
    size_t off = 0;
    auto alloc = [&](size_t bytes) -> void* {
        void* p = ws + off;
        off = (off + bytes + 255) & ~(size_t)255;
        return p;
    };
    // ---- zero-initialized region (single memset) ----
    float*          deg       = (float*)alloc((size_t)N * 4);
    int*            cnt       = (int*)alloc((size_t)N * 4);
    int*            cursor    = (int*)alloc((size_t)N * 4);
    float*          Ztf       = (float*)alloc((size_t)BQ * HIDDIM * 4);
    float*          Y         = (float*)alloc((size_t)N * BQ * 4);               // 5.1 MB
    size_t zero_bytes = off;
    // ---- rest ----
    int*            row_start = (int*)alloc((size_t)(N + 1) * 4);
    int*            src_s     = (int*)alloc((size_t)E * 4);
    float*          wnrm_s    = (float*)alloc((size_t)E * 4);
    unsigned short* aggNF     = (unsigned short*)alloc((size_t)N * KPAD1 * 2);   // 12.8 MB
    unsigned short* W1bt      = (unsigned short*)alloc((size_t)HIDDIM * KPAD1 * 2);
    unsigned short* x         = (unsigned short*)alloc((size_t)N * HIDDIM * 2);  // 41 MB
    unsigned short* W2b       = (unsigned short*)alloc((size_t)HIDDIM * OUTDIM * 2); // 3.4 MB
    unsigned short* imgb      = (unsigned short*)alloc((size_t)BQ * OUTDIM * 2);
    unsigned short* nfb       = (unsigned short*)alloc((size_t)N * FTEXT * 2);   // 12 MB
    unsigned short* Zt        = (unsigned short*)alloc((size_t)BQ * HIDDIM * 2);
    float*          cvec      = (float*)alloc((size_t)BQ * 4);

    hipMemsetAsync(ws, 0, zero_bytes, stream);

    int eb = (E + 255) / 256;
    degcnt_kernel<<<eb, 256, 0, stream>>>(edge_dst, edge_weight, deg, cnt, E);
    scan_kernel<<<1, 1024, 0, stream>>>(cnt, row_start, N);
    fill_kernel<<<eb, 256, 0, stream>>>(edge_dst, edge_src, edge_weight, deg, row_start,
                                        cursor, src_s, wnrm_s, E);

    // all conversions (W1 transpose, W2, img, nf) in one wide kernel
    cvt_all_kernel<<<(W1N + (N1F4 + N2F4 + N3F4) + 255) / 256, 256, 0, stream>>>(
        W1, W1bt, W2, W2b, img_feat, imgb, node_features, nfb);

    // Ztf = img @ W2^T  [64 x 1024]  (MFMA, split-K=13, fp32 atomic)
    mfma_gemm<0, 0, 1, 64><<<dim3(HIDDIM / 64, 1, 13), 256, 0, stream>>>(
        imgb, W2b, nullptr, Ztf, BQ, HIDDIM, OUTDIM, HIDDIM);
    // Zt = bf16(Ztf); cvec = img.b2
    ztcvec_kernel<<<(BQ * HIDDIM) / 256 + BQ, 256, 0, stream>>>(Ztf, Zt, img_feat, b2, cvec);

    // aggNF = bf16(A @ nfb), k-padded
    aggnf_kernel<<<N / 4, 256, 0, stream>>>(nfb, row_start, src_s, wnrm_s, aggNF);

    // x = bf16(leaky(aggNF @ W1 + b1))   [N x 1024]   (MFMA, 128x128 tile)
    mfma_gemm<1, 1, 0, 128><<<dim3(HIDDIM / 128, (N + 127) / 128, 1), 256, 0, stream>>>(
        aggNF, W1bt, b1, x, N, HIDDIM, KPAD1, HIDDIM);

    // Y += x @ Zt^T   [N x 64]   (MFMA, split-K=4, fp32 atomic accumulate)
    mfma_gemm<0, 0, 1, 64><<<dim3(1, (N + 127) / 128, 4), 256, 0, stream>>>(
        x, Zt, nullptr, Y, N, BQ, HIDDIM, BQ);

    outagg_kernel<<<N / 4, 256, 0, stream>>>(Y, row_start, src_s, wnrm_s, cvec, out, N);
}

// Round 9
// 246.436 us; speedup vs baseline: 3.4443x; 1.0963x over previous
//
#include <hip/hip_runtime.h>
#include <hip/hip_bf16.h>

#define NNODES 20000
#define NEDGES 160000
#define BQ     64
#define FTEXT  300
#define KPAD1  320          // FTEXT padded to multiple of 32
#define HIDDIM 1024
#define OUTDIM 1664

typedef __attribute__((ext_vector_type(8))) short short8;
typedef __attribute__((ext_vector_type(4))) float floatx4;

__device__ inline unsigned short f2bf(float f) {
    union { float f; unsigned int u; } v; v.f = f;
    unsigned int r = v.u + 0x7FFF + ((v.u >> 16) & 1);   // RNE
    return (unsigned short)(r >> 16);
}
__device__ inline float bf2f(unsigned short h) {
    union { unsigned int u; float f; } v; v.u = ((unsigned int)h) << 16;
    return v.f;
}

// ---------------- degree + count ----------------
__global__ void degcnt_kernel(const int* __restrict__ dst, const float* __restrict__ w,
                              float* __restrict__ deg, int* __restrict__ cnt, int E) {
    int e = blockIdx.x * blockDim.x + threadIdx.x;
    if (e < E) {
        int d = dst[e];
        atomicAdd(&deg[d], w[e]);
        atomicAdd(&cnt[d], 1);
    }
}

// ---------------- CSR scan: 1024 threads, int4-vectorized, LDS prefix --------
__global__ __launch_bounds__(1024) void scan_kernel(const int* __restrict__ cnt,
                                                    int* __restrict__ row_start, int N) {
    __shared__ int partial[1024];
    const int CH = 20;
    int t = threadIdx.x;
    int begin = t * CH;
    int nloc = N - begin; if (nloc > CH) nloc = CH; if (nloc < 0) nloc = 0;
    int vals[CH];
    int s = 0;
    if (nloc == CH) {
        #pragma unroll
        for (int i = 0; i < CH / 4; i++) {
            int4 v = ((const int4*)(cnt + begin))[i];
            vals[i*4+0] = v.x; vals[i*4+1] = v.y; vals[i*4+2] = v.z; vals[i*4+3] = v.w;
            s += v.x + v.y + v.z + v.w;
        }
    } else {
        for (int i = 0; i < nloc; i++) { vals[i] = cnt[begin + i]; s += vals[i]; }
    }
    partial[t] = s;
    __syncthreads();
    for (int off = 1; off < 1024; off <<= 1) {
        int v = (t >= off) ? partial[t - off] : 0;
        __syncthreads();
        partial[t] += v;
        __syncthreads();
    }
    int run = (t == 0) ? 0 : partial[t - 1];
    for (int i = 0; i < nloc; i++) { row_start[begin + i] = run; run += vals[i]; }
    if (t == 1023) row_start[N] = partial[1023];
}

// fill dst-sorted edge arrays with INLINE norm: wnrm = dinv[src]*w*dinv[dst]
__global__ void fill_kernel(const int* __restrict__ dst, const int* __restrict__ src,
                            const float* __restrict__ w, const float* __restrict__ deg,
                            const int* __restrict__ row_start, int* __restrict__ cursor,
                            int* __restrict__ src_s, float* __restrict__ wnrm_s, int E) {
    int e = blockIdx.x * blockDim.x + threadIdx.x;
    if (e < E) {
        int d = dst[e], s = src[e];
        float dd = deg[d], ds = deg[s];
        float nv = (ds > 0.f ? rsqrtf(ds) : 0.f) * w[e] * (dd > 0.f ? rsqrtf(dd) : 0.f);
        int pos = row_start[d] + atomicAdd(&cursor[d], 1);
        src_s[pos] = s;
        wnrm_s[pos] = nv;
    }
}

// ---------------- aggNF[d, 0:320] (bf16, zero-padded) = sum w*nfb[src,:] -------
// wave per node; edge metadata preloaded lane-parallel + __shfl broadcast;
// gathers software-pipelined one-ahead; both f4 chunks in one edge walk (ILP).
__global__ __launch_bounds__(256) void aggnf_kernel(const unsigned short* __restrict__ nfb,
        const int* __restrict__ row_start, const int* __restrict__ src_s,
        const float* __restrict__ wnrm_s, unsigned short* __restrict__ out) {
    int wave = threadIdx.x >> 6, lane = threadIdx.x & 63;
    int d = blockIdx.x * 4 + wave;
    int s0 = row_start[d], s1 = row_start[d + 1];
    float4 acc  = make_float4(0.f, 0.f, 0.f, 0.f);   // f4 = lane
    float4 acc2 = make_float4(0.f, 0.f, 0.f, 0.f);   // f4 = 64+lane (lane<11)
    for (int base = s0; base < s1; base += 64) {
        int m = s1 - base; if (m > 64) m = 64;
        int   src_l = (lane < m) ? src_s[base + lane]  : 0;
        float w_l   = (lane < m) ? wnrm_s[base + lane] : 0.f;
        int sj = __shfl(src_l, 0);
        float wj = __shfl(w_l, 0);
        const ushort4* row = (const ushort4*)(nfb + (long)sj * FTEXT);
        ushort4 hv  = row[lane];
        ushort4 hv2 = make_ushort4(0, 0, 0, 0);
        if (lane < 11) hv2 = row[64 + lane];
        for (int j = 0; j < m; j++) {
            ushort4 nv  = make_ushort4(0, 0, 0, 0);
            ushort4 nv2 = make_ushort4(0, 0, 0, 0);
            float wn = 0.f;
            if (j + 1 < m) {
                int sn = __shfl(src_l, j + 1);
                wn = __shfl(w_l, j + 1);
                const ushort4* nrow = (const ushort4*)(nfb + (long)sn * FTEXT);
                nv = nrow[lane];
                if (lane < 11) nv2 = nrow[64 + lane];
            }
            acc.x  += bf2f(hv.x)  * wj; acc.y  += bf2f(hv.y)  * wj;
            acc.z  += bf2f(hv.z)  * wj; acc.w  += bf2f(hv.w)  * wj;
            acc2.x += bf2f(hv2.x) * wj; acc2.y += bf2f(hv2.y) * wj;
            acc2.z += bf2f(hv2.z) * wj; acc2.w += bf2f(hv2.w) * wj;
            hv = nv; hv2 = nv2; wj = wn;
        }
    }
    unsigned short* orow = out + (long)d * KPAD1;
    ushort4 o;
    o.x = f2bf(acc.x); o.y = f2bf(acc.y); o.z = f2bf(acc.z); o.w = f2bf(acc.w);
    ((ushort4*)orow)[lane] = o;
    if (lane < 16) {   // f4 64..74 = data, 75..79 = zero pad
        ushort4 o2 = make_ushort4(0, 0, 0, 0);
        if (lane < 11) {
            o2.x = f2bf(acc2.x); o2.y = f2bf(acc2.y);
            o2.z = f2bf(acc2.z); o2.w = f2bf(acc2.w);
        }
        ((ushort4*)orow)[64 + lane] = o2;
    }
}

// ---------------- all weight/input conversions in ONE kernel ------------------
#define W1N  (HIDDIM * KPAD1)
#define N1F4 (HIDDIM * OUTDIM / 4)
#define N2F4 (BQ * OUTDIM / 4)
#define N3F4 (NNODES * FTEXT / 4)
__global__ void cvt_all_kernel(const float* __restrict__ W1, unsigned short* __restrict__ W1bt,
                               const float* __restrict__ W2, unsigned short* __restrict__ W2b,
                               const float* __restrict__ img, unsigned short* __restrict__ imgb,
                               const float* __restrict__ nf, unsigned short* __restrict__ nfb) {
    int i = blockIdx.x * 256 + threadIdx.x;
    if (i < W1N) {
        int n = i / KPAD1, k = i % KPAD1;
        float v = (k < FTEXT) ? W1[(long)k * HIDDIM + n] : 0.f;
        W1bt[i] = f2bf(v);
        return;
    }
    i -= W1N;
    const float* in; unsigned short* outp; int j;
    if (i < N1F4)                    { in = W2;  outp = W2b;  j = i; }
    else if (i < N1F4 + N2F4)        { in = img; outp = imgb; j = i - N1F4; }
    else if (i < N1F4 + N2F4 + N3F4) { in = nf;  outp = nfb;  j = i - N1F4 - N2F4; }
    else return;
    float4 v = ((const float4*)in)[j];
    ushort4 o;
    o.x = f2bf(v.x); o.y = f2bf(v.y); o.z = f2bf(v.z); o.w = f2bf(v.w);
    ((ushort4*)outp)[j] = o;
}

// ---------------- Zt = bf16(Ztf)  +  cvec[b] = img[b,:].b2  (one kernel) ------
__global__ __launch_bounds__(256) void ztcvec_kernel(const float* __restrict__ Ztf,
        unsigned short* __restrict__ Zt, const float* __restrict__ img,
        const float* __restrict__ b2, float* __restrict__ cvec) {
    if (blockIdx.x < (BQ * HIDDIM) / 256) {
        int i = blockIdx.x * 256 + threadIdx.x;
        Zt[i] = f2bf(Ztf[i]);
    } else {
        int b = blockIdx.x - (BQ * HIDDIM) / 256;
        int l = threadIdx.x;
        float v = 0.f;
        for (int f = l; f < OUTDIM; f += 256) v += img[(long)b * OUTDIM + f] * b2[f];
        __shared__ float red[256];
        red[l] = v;
        __syncthreads();
        if (l < 64) {
            v = red[l] + red[l + 64] + red[l + 128] + red[l + 192];
            for (int off = 32; off > 0; off >>= 1) v += __shfl_down(v, off);
            if (l == 0) cvec[b] = v;
        }
    }
}

// ---------------- bf16 MFMA GEMM: C[M x N] = A[M x K] @ B^T, B is [N x K] ------
template<int EPI, int OUT_BF16, int ATOMIC, int NT>
__global__ __launch_bounds__(256) void mfma_gemm(
        const unsigned short* __restrict__ A, const unsigned short* __restrict__ B,
        const float* __restrict__ bias, void* __restrict__ Cv,
        int M, int N, int K, int ldc) {
    constexpr int CT = NT / 16;
    __shared__ unsigned short As[128][40];
    __shared__ unsigned short Bs[NT][40];
    int t = threadIdx.x;
    int m0 = blockIdx.y * 128;
    int n0 = blockIdx.x * NT;
    int klen = K / gridDim.z;
    int kbeg = blockIdx.z * klen;
    int wave = t >> 6, lane = t & 63;
    int lm = lane & 15, lq = lane >> 4;
    floatx4 acc[2][CT] = {};
    for (int k0 = kbeg; k0 < kbeg + klen; k0 += 32) {
        #pragma unroll
        for (int p = 0; p < 2; p++) {
            int idx = p * 256 + t;
            int r = idx >> 2, c8 = (idx & 3) * 8;
            uint4 v = make_uint4(0, 0, 0, 0);
            int gm = m0 + r;
            if (gm < M) v = *(const uint4*)(A + (long)gm * K + k0 + c8);
            *(uint4*)&As[r][c8] = v;
        }
        #pragma unroll
        for (int p = 0; p < NT / 64; p++) {
            int idx = p * 256 + t;
            int r = idx >> 2, c8 = (idx & 3) * 8;
            uint4 v = *(const uint4*)(B + (long)(n0 + r) * K + k0 + c8);
            *(uint4*)&Bs[r][c8] = v;
        }
        __syncthreads();
        short8 a[2], b[CT];
        #pragma unroll
        for (int rt = 0; rt < 2; rt++)
            a[rt] = *(const short8*)&As[wave * 32 + rt * 16 + lm][lq * 8];
        #pragma unroll
        for (int ct = 0; ct < CT; ct++)
            b[ct] = *(const short8*)&Bs[ct * 16 + lm][lq * 8];
        #pragma unroll
        for (int rt = 0; rt < 2; rt++)
            #pragma unroll
            for (int ct = 0; ct < CT; ct++)
                acc[rt][ct] = __builtin_amdgcn_mfma_f32_16x16x32_bf16(
                    a[rt], b[ct], acc[rt][ct], 0, 0, 0);
        __syncthreads();
    }
    #pragma unroll
    for (int rt = 0; rt < 2; rt++) {
        #pragma unroll
        for (int r = 0; r < 4; r++) {
            int gm = m0 + wave * 32 + rt * 16 + lq * 4 + r;
            if (gm >= M) continue;
            #pragma unroll
            for (int ct = 0; ct < CT; ct++) {
                int gn = n0 + ct * 16 + lm;
                float v = acc[rt][ct][r];
                if (EPI) { v += bias[gn]; v = v >= 0.f ? v : 0.2f * v; }
                if (OUT_BF16)      ((unsigned short*)Cv)[(long)gm * ldc + gn] = f2bf(v);
                else if (ATOMIC)   atomicAdd((float*)Cv + (long)gm * ldc + gn, v);
                else               ((float*)Cv)[(long)gm * ldc + gn] = v;
            }
        }
    }
}

// ---------------- out[b,d] = sum_{e:dst=d} w*Y[src,b] + c[b] ------------------
// wave per node; lane-preload + shfl edge metadata; pipelined Y gathers.
__global__ __launch_bounds__(256) void outagg_kernel(const float* __restrict__ Y,
        const int* __restrict__ row_start, const int* __restrict__ src_s,
        const float* __restrict__ wnrm_s, const float* __restrict__ c,
        float* __restrict__ out, int N) {
    __shared__ float tile[4][68];
    int d0 = blockIdx.x * 4;
    int t = threadIdx.x;
    int wave = t >> 6, lane = t & 63;
    int d = d0 + wave;
    int s0 = row_start[d], s1 = row_start[d + 1];
    float acc = 0.f;
    for (int base = s0; base < s1; base += 64) {
        int m = s1 - base; if (m > 64) m = 64;
        int   src_l = (lane < m) ? src_s[base + lane]  : 0;
        float w_l   = (lane < m) ? wnrm_s[base + lane] : 0.f;
        int sj = __shfl(src_l, 0);
        float wj = __shfl(w_l, 0);
        float yv = Y[(long)sj * 64 + lane];
        for (int j = 0; j < m; j++) {
            float yn = 0.f, wn = 0.f;
            if (j + 1 < m) {
                int sn = __shfl(src_l, j + 1);
                wn = __shfl(w_l, j + 1);
                yn = Y[(long)sn * 64 + lane];
            }
            acc += wj * yv;
            yv = yn; wj = wn;
        }
    }
    tile[wave][lane] = acc + c[lane];
    __syncthreads();
    int b = t >> 2, j = t & 3;
    out[(long)b * N + d0 + j] = tile[j][b];
}

extern "C" void kernel_launch(void* const* d_in, const int* in_sizes, int n_in,
                              void* d_out, int out_size, void* d_ws, size_t ws_size,
                              hipStream_t stream) {
    const float* img_feat      = (const float*)d_in[0];
    const float* node_features = (const float*)d_in[1];
    const int*   edge_src      = (const int*)d_in[2];
    const int*   edge_dst      = (const int*)d_in[3];
    const float* edge_weight   = (const float*)d_in[4];
    const float* W1            = (const float*)d_in[5];
    const float* b1            = (const float*)d_in[6];
    const float* W2            = (const float*)d_in[7];
    const float* b2            = (const float*)d_in[8];
    float* out = (float*)d_out;

    const int N = NNODES, E = NEDGES;

    char* ws = (char*)d_ws;
    size_t off = 0;
    auto alloc = [&](size_t bytes) -> void* {
        void* p = ws + off;
        off = (off + bytes + 255) & ~(size_t)255;
        return p;
    };
    // ---- zero-initialized region (single memset) ----
    float*          deg       = (float*)alloc((size_t)N * 4);
    int*            cnt       = (int*)alloc((size_t)N * 4);
    int*            cursor    = (int*)alloc((size_t)N * 4);
    float*          Ztf       = (float*)alloc((size_t)BQ * HIDDIM * 4);
    float*          Y         = (float*)alloc((size_t)N * BQ * 4);
    size_t zero_bytes = off;
    // ---- rest ----
    int*            row_start = (int*)alloc((size_t)(N + 1) * 4);
    int*            src_s     = (int*)alloc((size_t)E * 4);
    float*          wnrm_s    = (float*)alloc((size_t)E * 4);
    unsigned short* aggNF     = (unsigned short*)alloc((size_t)N * KPAD1 * 2);
    unsigned short* W1bt      = (unsigned short*)alloc((size_t)HIDDIM * KPAD1 * 2);
    unsigned short* x         = (unsigned short*)alloc((size_t)N * HIDDIM * 2);
    unsigned short* W2b       = (unsigned short*)alloc((size_t)HIDDIM * OUTDIM * 2);
    unsigned short* imgb      = (unsigned short*)alloc((size_t)BQ * OUTDIM * 2);
    unsigned short* nfb       = (unsigned short*)alloc((size_t)N * FTEXT * 2);
    unsigned short* Zt        = (unsigned short*)alloc((size_t)BQ * HIDDIM * 2);
    float*          cvec      = (float*)alloc((size_t)BQ * 4);

    hipMemsetAsync(ws, 0, zero_bytes, stream);

    int eb = (E + 255) / 256;
    degcnt_kernel<<<eb, 256, 0, stream>>>(edge_dst, edge_weight, deg, cnt, E);
    scan_kernel<<<1, 1024, 0, stream>>>(cnt, row_start, N);
    fill_kernel<<<eb, 256, 0, stream>>>(edge_dst, edge_src, edge_weight, deg, row_start,
                                        cursor, src_s, wnrm_s, E);

    cvt_all_kernel<<<(W1N + (N1F4 + N2F4 + N3F4) + 255) / 256, 256, 0, stream>>>(
        W1, W1bt, W2, W2b, img_feat, imgb, node_features, nfb);

    // Ztf = img @ W2^T  [64 x 1024]  (MFMA, split-K=13, fp32 atomic)
    mfma_gemm<0, 0, 1, 64><<<dim3(HIDDIM / 64, 1, 13), 256, 0, stream>>>(
        imgb, W2b, nullptr, Ztf, BQ, HIDDIM, OUTDIM, HIDDIM);
    ztcvec_kernel<<<(BQ * HIDDIM) / 256 + BQ, 256, 0, stream>>>(Ztf, Zt, img_feat, b2, cvec);

    // aggNF = bf16(A @ nfb), k-padded
    aggnf_kernel<<<N / 4, 256, 0, stream>>>(nfb, row_start, src_s, wnrm_s, aggNF);

    // x = bf16(leaky(aggNF @ W1 + b1))   [N x 1024]   (MFMA, 128x128 tile)
    mfma_gemm<1, 1, 0, 128><<<dim3(HIDDIM / 128, (N + 127) / 128, 1), 256, 0, stream>>>(
        aggNF, W1bt, b1, x, N, HIDDIM, KPAD1, HIDDIM);

    // Y += x @ Zt^T   [N x 64]   (MFMA, split-K=4, fp32 atomic accumulate)
    mfma_gemm<0, 0, 1, 64><<<dim3(1, (N + 127) / 128, 4), 256, 0, stream>>>(
        x, Zt, nullptr, Y, N, BQ, HIDDIM, BQ);

    outagg_kernel<<<N / 4, 256, 0, stream>>>(Y, row_start, src_s, wnrm_s, cvec, out, N);
}

// Round 11
// 243.487 us; speedup vs baseline: 3.4860x; 1.0121x over previous
//
#include <hip/hip_runtime.h>
#include <hip/hip_bf16.h>

#define NNODES 20000
#define NEDGES 160000
#define BQ     64
#define FTEXT  300
#define KPAD1  320          // FTEXT padded to multiple of 32
#define HIDDIM 1024
#define OUTDIM 1664

typedef __attribute__((ext_vector_type(8))) short short8;
typedef __attribute__((ext_vector_type(4))) float floatx4;

__device__ inline unsigned short f2bf(float f) {
    union { float f; unsigned int u; } v; v.f = f;
    unsigned int r = v.u + 0x7FFF + ((v.u >> 16) & 1);   // RNE
    return (unsigned short)(r >> 16);
}
__device__ inline float bf2f(unsigned short h) {
    union { unsigned int u; float f; } v; v.u = ((unsigned int)h) << 16;
    return v.f;
}

// ---------------- degree + count ----------------
__global__ void degcnt_kernel(const int* __restrict__ dst, const float* __restrict__ w,
                              float* __restrict__ deg, int* __restrict__ cnt, int E) {
    int e = blockIdx.x * blockDim.x + threadIdx.x;
    if (e < E) {
        int d = dst[e];
        atomicAdd(&deg[d], w[e]);
        atomicAdd(&cnt[d], 1);
    }
}

// ---------------- CSR scan ----------------
__global__ __launch_bounds__(1024) void scan_kernel(const int* __restrict__ cnt,
                                                    int* __restrict__ row_start, int N) {
    __shared__ int partial[1024];
    const int CH = 20;
    int t = threadIdx.x;
    int begin = t * CH;
    int nloc = N - begin; if (nloc > CH) nloc = CH; if (nloc < 0) nloc = 0;
    int vals[CH];
    int s = 0;
    if (nloc == CH) {
        #pragma unroll
        for (int i = 0; i < CH / 4; i++) {
            int4 v = ((const int4*)(cnt + begin))[i];
            vals[i*4+0] = v.x; vals[i*4+1] = v.y; vals[i*4+2] = v.z; vals[i*4+3] = v.w;
            s += v.x + v.y + v.z + v.w;
        }
    } else {
        for (int i = 0; i < nloc; i++) { vals[i] = cnt[begin + i]; s += vals[i]; }
    }
    partial[t] = s;
    __syncthreads();
    for (int off = 1; off < 1024; off <<= 1) {
        int v = (t >= off) ? partial[t - off] : 0;
        __syncthreads();
        partial[t] += v;
        __syncthreads();
    }
    int run = (t == 0) ? 0 : partial[t - 1];
    for (int i = 0; i < nloc; i++) { row_start[begin + i] = run; run += vals[i]; }
    if (t == 1023) row_start[N] = partial[1023];
}

// fill dst-sorted edge arrays with INLINE norm
__global__ void fill_kernel(const int* __restrict__ dst, const int* __restrict__ src,
                            const float* __restrict__ w, const float* __restrict__ deg,
                            const int* __restrict__ row_start, int* __restrict__ cursor,
                            int* __restrict__ src_s, float* __restrict__ wnrm_s, int E) {
    int e = blockIdx.x * blockDim.x + threadIdx.x;
    if (e < E) {
        int d = dst[e], s = src[e];
        float dd = deg[d], ds = deg[s];
        float nv = (ds > 0.f ? rsqrtf(ds) : 0.f) * w[e] * (dd > 0.f ? rsqrtf(dd) : 0.f);
        int pos = row_start[d] + atomicAdd(&cursor[d], 1);
        src_s[pos] = s;
        wnrm_s[pos] = nv;
    }
}

// ---------------- aggNF[d, 0:320] (bf16, zero-padded) = sum w*nfb[src,:] -------
__global__ __launch_bounds__(256) void aggnf_kernel(const unsigned short* __restrict__ nfb,
        const int* __restrict__ row_start, const int* __restrict__ src_s,
        const float* __restrict__ wnrm_s, unsigned short* __restrict__ out) {
    int wave = threadIdx.x >> 6, lane = threadIdx.x & 63;
    int d = blockIdx.x * 4 + wave;
    int s0 = row_start[d], s1 = row_start[d + 1];
    float4 acc  = make_float4(0.f, 0.f, 0.f, 0.f);
    float4 acc2 = make_float4(0.f, 0.f, 0.f, 0.f);
    for (int base = s0; base < s1; base += 64) {
        int m = s1 - base; if (m > 64) m = 64;
        int   src_l = (lane < m) ? src_s[base + lane]  : 0;
        float w_l   = (lane < m) ? wnrm_s[base + lane] : 0.f;
        int sj = __shfl(src_l, 0);
        float wj = __shfl(w_l, 0);
        const ushort4* row = (const ushort4*)(nfb + (long)sj * FTEXT);
        ushort4 hv  = row[lane];
        ushort4 hv2 = make_ushort4(0, 0, 0, 0);
        if (lane < 11) hv2 = row[64 + lane];
        for (int j = 0; j < m; j++) {
            ushort4 nv  = make_ushort4(0, 0, 0, 0);
            ushort4 nv2 = make_ushort4(0, 0, 0, 0);
            float wn = 0.f;
            if (j + 1 < m) {
                int sn = __shfl(src_l, j + 1);
                wn = __shfl(w_l, j + 1);
                const ushort4* nrow = (const ushort4*)(nfb + (long)sn * FTEXT);
                nv = nrow[lane];
                if (lane < 11) nv2 = nrow[64 + lane];
            }
            acc.x  += bf2f(hv.x)  * wj; acc.y  += bf2f(hv.y)  * wj;
            acc.z  += bf2f(hv.z)  * wj; acc.w  += bf2f(hv.w)  * wj;
            acc2.x += bf2f(hv2.x) * wj; acc2.y += bf2f(hv2.y) * wj;
            acc2.z += bf2f(hv2.z) * wj; acc2.w += bf2f(hv2.w) * wj;
            hv = nv; hv2 = nv2; wj = wn;
        }
    }
    unsigned short* orow = out + (long)d * KPAD1;
    ushort4 o;
    o.x = f2bf(acc.x); o.y = f2bf(acc.y); o.z = f2bf(acc.z); o.w = f2bf(acc.w);
    ((ushort4*)orow)[lane] = o;
    if (lane < 16) {
        ushort4 o2 = make_ushort4(0, 0, 0, 0);
        if (lane < 11) {
            o2.x = f2bf(acc2.x); o2.y = f2bf(acc2.y);
            o2.z = f2bf(acc2.z); o2.w = f2bf(acc2.w);
        }
        ((ushort4*)orow)[64 + lane] = o2;
    }
}

// ---------------- all weight/input conversions in ONE kernel ------------------
#define W1N  (HIDDIM * KPAD1)
#define N1F4 (HIDDIM * OUTDIM / 4)
#define N2F4 (BQ * OUTDIM / 4)
#define N3F4 (NNODES * FTEXT / 4)
__global__ void cvt_all_kernel(const float* __restrict__ W1, unsigned short* __restrict__ W1bt,
                               const float* __restrict__ W2, unsigned short* __restrict__ W2b,
                               const float* __restrict__ img, unsigned short* __restrict__ imgb,
                               const float* __restrict__ nf, unsigned short* __restrict__ nfb) {
    int i = blockIdx.x * 256 + threadIdx.x;
    if (i < W1N) {
        int n = i / KPAD1, k = i % KPAD1;
        float v = (k < FTEXT) ? W1[(long)k * HIDDIM + n] : 0.f;
        W1bt[i] = f2bf(v);
        return;
    }
    i -= W1N;
    const float* in; unsigned short* outp; int j;
    if (i < N1F4)                    { in = W2;  outp = W2b;  j = i; }
    else if (i < N1F4 + N2F4)        { in = img; outp = imgb; j = i - N1F4; }
    else if (i < N1F4 + N2F4 + N3F4) { in = nf;  outp = nfb;  j = i - N1F4 - N2F4; }
    else return;
    float4 v = ((const float4*)in)[j];
    ushort4 o;
    o.x = f2bf(v.x); o.y = f2bf(v.y); o.z = f2bf(v.z); o.w = f2bf(v.w);
    ((ushort4*)outp)[j] = o;
}

// ---------------- Zt = bf16(Ztf)  +  cvec[b] = img[b,:].b2 --------------------
__global__ __launch_bounds__(256) void ztcvec_kernel(const float* __restrict__ Ztf,
        unsigned short* __restrict__ Zt, const float* __restrict__ img,
        const float* __restrict__ b2, float* __restrict__ cvec) {
    if (blockIdx.x < (BQ * HIDDIM) / 256) {
        int i = blockIdx.x * 256 + threadIdx.x;
        Zt[i] = f2bf(Ztf[i]);
    } else {
        int b = blockIdx.x - (BQ * HIDDIM) / 256;
        int l = threadIdx.x;
        float v = 0.f;
        for (int f = l; f < OUTDIM; f += 256) v += img[(long)b * OUTDIM + f] * b2[f];
        __shared__ float red[256];
        red[l] = v;
        __syncthreads();
        if (l < 64) {
            v = red[l] + red[l + 64] + red[l + 128] + red[l + 192];
            for (int off = 32; off > 0; off >>= 1) v += __shfl_down(v, off);
            if (l == 0) cvec[b] = v;
        }
    }
}

// ---------------- bf16 MFMA GEMM (used for Zt only now) -----------------------
template<int EPI, int OUT_BF16, int ATOMIC, int NT>
__global__ __launch_bounds__(256) void mfma_gemm(
        const unsigned short* __restrict__ A, const unsigned short* __restrict__ B,
        const float* __restrict__ bias, void* __restrict__ Cv,
        int M, int N, int K, int ldc) {
    constexpr int CT = NT / 16;
    __shared__ unsigned short As[128][40];
    __shared__ unsigned short Bs[NT][40];
    int t = threadIdx.x;
    int m0 = blockIdx.y * 128;
    int n0 = blockIdx.x * NT;
    int klen = K / gridDim.z;
    int kbeg = blockIdx.z * klen;
    int wave = t >> 6, lane = t & 63;
    int lm = lane & 15, lq = lane >> 4;
    floatx4 acc[2][CT] = {};
    for (int k0 = kbeg; k0 < kbeg + klen; k0 += 32) {
        #pragma unroll
        for (int p = 0; p < 2; p++) {
            int idx = p * 256 + t;
            int r = idx >> 2, c8 = (idx & 3) * 8;
            uint4 v = make_uint4(0, 0, 0, 0);
            int gm = m0 + r;
            if (gm < M) v = *(const uint4*)(A + (long)gm * K + k0 + c8);
            *(uint4*)&As[r][c8] = v;
        }
        #pragma unroll
        for (int p = 0; p < NT / 64; p++) {
            int idx = p * 256 + t;
            int r = idx >> 2, c8 = (idx & 3) * 8;
            uint4 v = *(const uint4*)(B + (long)(n0 + r) * K + k0 + c8);
            *(uint4*)&Bs[r][c8] = v;
        }
        __syncthreads();
        short8 a[2], b[CT];
        #pragma unroll
        for (int rt = 0; rt < 2; rt++)
            a[rt] = *(const short8*)&As[wave * 32 + rt * 16 + lm][lq * 8];
        #pragma unroll
        for (int ct = 0; ct < CT; ct++)
            b[ct] = *(const short8*)&Bs[ct * 16 + lm][lq * 8];
        #pragma unroll
        for (int rt = 0; rt < 2; rt++)
            #pragma unroll
            for (int ct = 0; ct < CT; ct++)
                acc[rt][ct] = __builtin_amdgcn_mfma_f32_16x16x32_bf16(
                    a[rt], b[ct], acc[rt][ct], 0, 0, 0);
        __syncthreads();
    }
    #pragma unroll
    for (int rt = 0; rt < 2; rt++) {
        #pragma unroll
        for (int r = 0; r < 4; r++) {
            int gm = m0 + wave * 32 + rt * 16 + lq * 4 + r;
            if (gm >= M) continue;
            #pragma unroll
            for (int ct = 0; ct < CT; ct++) {
                int gn = n0 + ct * 16 + lm;
                float v = acc[rt][ct][r];
                if (EPI) { v += bias[gn]; v = v >= 0.f ? v : 0.2f * v; }
                if (OUT_BF16)      ((unsigned short*)Cv)[(long)gm * ldc + gn] = f2bf(v);
                else if (ATOMIC)   atomicAdd((float*)Cv + (long)gm * ldc + gn, v);
                else               ((float*)Cv)[(long)gm * ldc + gn] = v;
            }
        }
    }
}

// ---------------- FUSED: x-tile = leaky(aggNF@W1^T+b1); Y += x-tile @ Zt^T -----
// Grid (8 nt, 157 mstrip), 512 threads = 8 waves; wave owns one 16-row m-tile.
// blockIdx.x picks x-cols [nt*128, nt*128+128) == ygemm k-slice (8-way split-K).
// LDS union: As/Bs (K-loop) and xs (x-tile, 128x128, stride 136) share memory —
// As/Bs are dead after the loop's final barrier. 34.8 KB total.
__global__ __launch_bounds__(512) void xy_gemm(
        const unsigned short* __restrict__ aggNF, const unsigned short* __restrict__ W1bt,
        const float* __restrict__ b1, const unsigned short* __restrict__ Zt,
        float* __restrict__ Y, int M) {
    __shared__ unsigned short smem[128 * 136];           // 34816 B
    unsigned short (*As)[40]  = (unsigned short (*)[40])smem;          // 128x40
    unsigned short (*Bs)[40]  = (unsigned short (*)[40])(smem + 5120); // 128x40
    unsigned short (*xs)[136] = (unsigned short (*)[136])smem;         // 128x136 (reuse)
    int t = threadIdx.x;
    int wave = t >> 6, lane = t & 63;
    int lm = lane & 15, lq = lane >> 4;
    int m0 = blockIdx.y * 128;
    int n0 = blockIdx.x * 128;
    floatx4 acc[8] = {};
    // ---- GEMM1: x_tile = aggNF[m0:,:] @ W1bt[n0:,:]^T   (K=320) ----
    for (int k0 = 0; k0 < KPAD1; k0 += 32) {
        {
            int r = t >> 2, c8 = (t & 3) * 8;
            uint4 v = make_uint4(0, 0, 0, 0);
            int gm = m0 + r;
            if (gm < M) v = *(const uint4*)(aggNF + (long)gm * KPAD1 + k0 + c8);
            *(uint4*)&As[r][c8] = v;
        }
        {
            int r = t >> 2, c8 = (t & 3) * 8;
            uint4 v = *(const uint4*)(W1bt + (long)(n0 + r) * KPAD1 + k0 + c8);
            *(uint4*)&Bs[r][c8] = v;
        }
        __syncthreads();
        short8 a = *(const short8*)&As[wave * 16 + lm][lq * 8];
        #pragma unroll
        for (int ct = 0; ct < 8; ct++) {
            short8 b = *(const short8*)&Bs[ct * 16 + lm][lq * 8];
            acc[ct] = __builtin_amdgcn_mfma_f32_16x16x32_bf16(a, b, acc[ct], 0, 0, 0);
        }
        __syncthreads();   // all waves done reading As/Bs -> safe to overwrite as xs
    }
    // ---- epilogue 1: bias + leaky, C-layout -> xs (A-frag-readable) ----
    #pragma unroll
    for (int ct = 0; ct < 8; ct++) {
        int col = ct * 16 + lm;
        float bv = b1[n0 + col];
        #pragma unroll
        for (int r = 0; r < 4; r++) {
            float v = acc[ct][r] + bv;
            v = v >= 0.f ? v : 0.2f * v;
            xs[wave * 16 + lq * 4 + r][col] = f2bf(v);
        }
    }
    __syncthreads();
    // ---- GEMM2: Y[m0:,:] += x_tile @ Zt[:, n0:n0+128]^T ----
    floatx4 yacc[4] = {};
    #pragma unroll
    for (int kk = 0; kk < 4; kk++) {
        short8 a = *(const short8*)&xs[wave * 16 + lm][kk * 32 + lq * 8];
        #pragma unroll
        for (int bt = 0; bt < 4; bt++) {
            short8 b = *(const short8*)(Zt + (long)(bt * 16 + lm) * HIDDIM
                                            + n0 + kk * 32 + lq * 8);
            yacc[bt] = __builtin_amdgcn_mfma_f32_16x16x32_bf16(a, b, yacc[bt], 0, 0, 0);
        }
    }
    #pragma unroll
    for (int bt = 0; bt < 4; bt++) {
        #pragma unroll
        for (int r = 0; r < 4; r++) {
            int gm = m0 + wave * 16 + lq * 4 + r;
            if (gm < M) atomicAdd(&Y[(long)gm * 64 + bt * 16 + lm], yacc[bt][r]);
        }
    }
}

// ---------------- out[b,d] = sum_{e:dst=d} w*Y[src,b] + c[b] ------------------
__global__ __launch_bounds__(256) void outagg_kernel(const float* __restrict__ Y,
        const int* __restrict__ row_start, const int* __restrict__ src_s,
        const float* __restrict__ wnrm_s, const float* __restrict__ c,
        float* __restrict__ out, int N) {
    __shared__ float tile[4][68];
    int d0 = blockIdx.x * 4;
    int t = threadIdx.x;
    int wave = t >> 6, lane = t & 63;
    int d = d0 + wave;
    int s0 = row_start[d], s1 = row_start[d + 1];
    float acc = 0.f;
    for (int base = s0; base < s1; base += 64) {
        int m = s1 - base; if (m > 64) m = 64;
        int   src_l = (lane < m) ? src_s[base + lane]  : 0;
        float w_l   = (lane < m) ? wnrm_s[base + lane] : 0.f;
        int sj = __shfl(src_l, 0);
        float wj = __shfl(w_l, 0);
        float yv = Y[(long)sj * 64 + lane];
        for (int j = 0; j < m; j++) {
            float yn = 0.f, wn = 0.f;
            if (j + 1 < m) {
                int sn = __shfl(src_l, j + 1);
                wn = __shfl(w_l, j + 1);
                yn = Y[(long)sn * 64 + lane];
            }
            acc += wj * yv;
            yv = yn; wj = wn;
        }
    }
    tile[wave][lane] = acc + c[lane];
    __syncthreads();
    int b = t >> 2, j = t & 3;
    out[(long)b * N + d0 + j] = tile[j][b];
}

extern "C" void kernel_launch(void* const* d_in, const int* in_sizes, int n_in,
                              void* d_out, int out_size, void* d_ws, size_t ws_size,
                              hipStream_t stream) {
    const float* img_feat      = (const float*)d_in[0];
    const float* node_features = (const float*)d_in[1];
    const int*   edge_src      = (const int*)d_in[2];
    const int*   edge_dst      = (const int*)d_in[3];
    const float* edge_weight   = (const float*)d_in[4];
    const float* W1            = (const float*)d_in[5];
    const float* b1            = (const float*)d_in[6];
    const float* W2            = (const float*)d_in[7];
    const float* b2            = (const float*)d_in[8];
    float* out = (float*)d_out;

    const int N = NNODES, E = NEDGES;

    char* ws = (char*)d_ws;
    size_t off = 0;
    auto alloc = [&](size_t bytes) -> void* {
        void* p = ws + off;
        off = (off + bytes + 255) & ~(size_t)255;
        return p;
    };
    // ---- zero-initialized region (single memset) ----
    float*          deg       = (float*)alloc((size_t)N * 4);
    int*            cnt       = (int*)alloc((size_t)N * 4);
    int*            cursor    = (int*)alloc((size_t)N * 4);
    float*          Ztf       = (float*)alloc((size_t)BQ * HIDDIM * 4);
    float*          Y         = (float*)alloc((size_t)N * BQ * 4);
    size_t zero_bytes = off;
    // ---- rest ----
    int*            row_start = (int*)alloc((size_t)(N + 1) * 4);
    int*            src_s     = (int*)alloc((size_t)E * 4);
    float*          wnrm_s    = (float*)alloc((size_t)E * 4);
    unsigned short* aggNF     = (unsigned short*)alloc((size_t)N * KPAD1 * 2);
    unsigned short* W1bt      = (unsigned short*)alloc((size_t)HIDDIM * KPAD1 * 2);
    unsigned short* W2b       = (unsigned short*)alloc((size_t)HIDDIM * OUTDIM * 2);
    unsigned short* imgb      = (unsigned short*)alloc((size_t)BQ * OUTDIM * 2);
    unsigned short* nfb       = (unsigned short*)alloc((size_t)N * FTEXT * 2);
    unsigned short* Zt        = (unsigned short*)alloc((size_t)BQ * HIDDIM * 2);
    float*          cvec      = (float*)alloc((size_t)BQ * 4);

    hipMemsetAsync(ws, 0, zero_bytes, stream);

    int eb = (E + 255) / 256;
    degcnt_kernel<<<eb, 256, 0, stream>>>(edge_dst, edge_weight, deg, cnt, E);
    scan_kernel<<<1, 1024, 0, stream>>>(cnt, row_start, N);
    fill_kernel<<<eb, 256, 0, stream>>>(edge_dst, edge_src, edge_weight, deg, row_start,
                                        cursor, src_s, wnrm_s, E);

    cvt_all_kernel<<<(W1N + (N1F4 + N2F4 + N3F4) + 255) / 256, 256, 0, stream>>>(
        W1, W1bt, W2, W2b, img_feat, imgb, node_features, nfb);

    // Ztf = img @ W2^T  [64 x 1024]  (MFMA, split-K=13, fp32 atomic)
    mfma_gemm<0, 0, 1, 64><<<dim3(HIDDIM / 64, 1, 13), 256, 0, stream>>>(
        imgb, W2b, nullptr, Ztf, BQ, HIDDIM, OUTDIM, HIDDIM);
    ztcvec_kernel<<<(BQ * HIDDIM) / 256 + BQ, 256, 0, stream>>>(Ztf, Zt, img_feat, b2, cvec);

    // aggNF = bf16(A @ nfb), k-padded
    aggnf_kernel<<<N / 4, 256, 0, stream>>>(nfb, row_start, src_s, wnrm_s, aggNF);

    // FUSED: Y += leaky(aggNF @ W1 + b1) @ Zt^T   (x stays on-chip)
    xy_gemm<<<dim3(HIDDIM / 128, (N + 127) / 128), 512, 0, stream>>>(
        aggNF, W1bt, b1, Zt, Y, N);

    outagg_kernel<<<N / 4, 256, 0, stream>>>(Y, row_start, src_s, wnrm_s, cvec, out, N);
}